// Round 14
// baseline (551.262 us; speedup 1.0000x reference)
//
#include <hip/hip_runtime.h>
#include <stdint.h>

#define NEGF (-1.0e8f)
#define NCELL (512 * 512)
#define INVLN2 1.4426950408889634f
#define NIV 71  // intervals of 16 diagonals; skew 16/wave

// raw barrier: LDS ordering only (never drains vmcnt -> global ops stay in flight)
#define BAR() asm volatile("s_waitcnt lgkmcnt(0)\n\ts_barrier" ::: "memory")

#define REP16(X) X(0) X(1) X(2) X(3) X(4) X(5) X(6) X(7) X(8) X(9) X(10) X(11) X(12) X(13) X(14) X(15)
#define REP18(X) REP16(X) X(16) X(17)

__device__ __forceinline__ float exp2f_(float x) {
#if __has_builtin(__builtin_amdgcn_exp2f)
  return __builtin_amdgcn_exp2f(x);
#else
  return exp2f(x);
#endif
}
__device__ __forceinline__ float log2f_(float x) {
#if __has_builtin(__builtin_amdgcn_logf)
  return __builtin_amdgcn_logf(x);
#else
  return log2f(x);
#endif
}
__device__ __forceinline__ uint32_t pknorm16(float a, float b) {
#if __has_builtin(__builtin_amdgcn_cvt_pknorm_u16)
  typedef unsigned short u2v __attribute__((ext_vector_type(2)));
  union { u2v v; uint32_t u; } cv;
  cv.v = __builtin_amdgcn_cvt_pknorm_u16(a, b);
  return cv.u;
#else
  uint32_t pa = (uint32_t)(a * 65535.0f + 0.5f);
  uint32_t pb = (uint32_t)(b * 65535.0f + 0.5f);
  return pa | (pb << 16);
#endif
}

// DPP wave shifts: 0x138 wave_shr:1 (lane l <- l-1, lane0 <- old), 0x130 wave_shl:1 (lane l <- l+1, lane63 <- old)
__device__ __forceinline__ float dpp_shr1_f(float src, float old0) {
  return __int_as_float(__builtin_amdgcn_update_dpp(
      __float_as_int(old0), __float_as_int(src), 0x138, 0xF, 0xF, false));
}
__device__ __forceinline__ float dpp_shl1_f(float src, float old63) {
  return __int_as_float(__builtin_amdgcn_update_dpp(
      __float_as_int(old63), __float_as_int(src), 0x130, 0xF, 0xF, false));
}
__device__ __forceinline__ uint32_t dpp_shl1_u(uint32_t src, uint32_t old63) {
  return (uint32_t)__builtin_amdgcn_update_dpp((int)old63, (int)src, 0x130, 0xF, 0xF, false);
}

// offset of diagonal d; lo(d)=max(1,d-512)
__device__ __forceinline__ int offd(int d) {
  return (d <= 513) ? (((d - 2) * (d - 1)) >> 1)
                    : (NCELL - (((1025 - d) * (1026 - d)) >> 1));
}
__device__ __forceinline__ int dbase(int d) {
  const int lo = (d > 513) ? d - 512 : 1;
  return offd(d) - lo;
}

// forward softmax-LSE cell (base-2 domain)
__device__ __forceinline__ void fcell(float& nv, uint32_t& pk, float dg, float up0,
                                      float lf0, float th, float A2) {
  float up = up0 + A2, lf = lf0 + A2;
  float mx = fmaxf(fmaxf(dg, up), lf);
  float ed = exp2f_(dg - mx), eu = exp2f_(up - mx), el = exp2f_(lf - mx);
  float s = ed + eu + el;
  nv = th + mx + log2f_(s);
  float rs = __builtin_amdgcn_rcpf(s);
  pk = pknorm16(ed * rs, eu * rs);
}

// ---------------------------------------------------------------------------
// K1: T[22][512] = W_embed @ W_proj + b_proj
// ---------------------------------------------------------------------------
__global__ void k_T(const float* __restrict__ We, const float* __restrict__ Wp,
                    const float* __restrict__ bp, float* __restrict__ T) {
  int a = blockIdx.x, c = threadIdx.x;
  __shared__ float e[512];
  e[c] = We[a * 512 + c];
  __syncthreads();
  float acc = bp[c];
#pragma unroll 8
  for (int k = 0; k < 512; ++k) acc = fmaf(e[k], Wp[k * 512 + c], acc);
  T[a * 512 + c] = acc;
}

// ---------------------------------------------------------------------------
// K2: G2[a][a2] (stride 37) = (T T^T)/ln2 ; u,v gap LUTs
// ---------------------------------------------------------------------------
__global__ void k_G(const float* __restrict__ T, const float* __restrict__ Wg,
                    float* __restrict__ G, float* __restrict__ u, float* __restrict__ v) {
  __shared__ float Ts[22 * 516];
  for (int k = threadIdx.x; k < 22 * 512; k += 512) {
    int a = k >> 9, c = k & 511;
    Ts[a * 516 + c] = T[k];
  }
  __syncthreads();
  for (int idx = threadIdx.x; idx < 528; idx += 512) {
    float s = 0.f;
    if (idx < 484) {
      int a = idx / 22, a2 = idx - 22 * a;
      const float* pa = &Ts[a * 516];
      const float* pb = &Ts[a2 * 516];
      for (int c = 0; c < 512; ++c) s = fmaf(pa[c], pb[c], s);
      G[a * 37 + a2] = s * INVLN2;
    } else if (idx < 506) {
      int a = idx - 484;
      const float* pa = &Ts[a * 516];
      for (int c = 0; c < 512; ++c) s = fmaf(pa[c], Wg[c], s);
      u[a] = s;
    } else {
      int a = idx - 506;
      const float* pa = &Ts[a * 516];
      for (int c = 0; c < 512; ++c) s = fmaf(pa[c], Wg[512 + c], s);
      v[a] = s;
    }
  }
}

// ---------------------------------------------------------------------------
// K3: A2[b]
// ---------------------------------------------------------------------------
__global__ void k_A(const int* __restrict__ x, const int* __restrict__ y,
                    const float* __restrict__ u, const float* __restrict__ v,
                    const float* __restrict__ bg, float* __restrict__ A) {
  int b = blockIdx.x, t = threadIdx.x;
  const int* xb = x + b * 512;
  const int* yb = y + b * 512;
  float s = u[xb[t]] + u[xb[t + 256]] + v[yb[t]] + v[yb[t + 256]];
  for (int o = 32; o > 0; o >>= 1) s += __shfl_down(s, o, 64);
  __shared__ float w[4];
  if ((t & 63) == 0) w[t >> 6] = s;
  __syncthreads();
  if (t == 0) A[b] = ((w[0] + w[1] + w[2] + w[3]) * (1.0f / 512.0f) + bg[0]) * INVLN2;
}

// ---------------------------------------------------------------------------
// K3b: theta precompute, diag-major: thD[b][offd(d)+ (i-lo)] = G2[x[b,i], y[b,d-i]]
//      128 blocks = 16 batches x 8 diag-segments; 512 threads.
// ---------------------------------------------------------------------------
__global__ __launch_bounds__(512) void k_th(const int* __restrict__ x, const int* __restrict__ y,
                                            const float* __restrict__ G,
                                            float* __restrict__ thD) {
  const int blk = blockIdx.x;
  const int b = blk >> 3, seg = blk & 7;
  __shared__ float Gl[814];
  __shared__ int xs[512], ys[512];
  const int tid = threadIdx.x;
  xs[tid] = x[b * 512 + tid];
  ys[tid] = y[b * 512 + tid];
  for (int k = tid; k < 814; k += 512) Gl[k] = G[k];
  __syncthreads();
  float* th = thD + (size_t)b * NCELL;
  for (int d = 2 + seg; d <= 1024; d += 8) {
    const int lo = (d > 513) ? d - 512 : 1;
    const int hi = (d - 1 < 512) ? d - 1 : 512;
    const int i = lo + tid;
    if (i <= hi) th[offd(d) + tid] = Gl[xs[i - 1] * 37 + ys[d - i - 1]];
  }
}

// ---------------------------------------------------------------------------
// K4: skewed 8-wave pipeline DP, KD=16, gating. Theta read from global
//     (diag-major, prefetched 1 interval ahead like backward's q pipeline).
//     LDS = boundary rings only.
// ---------------------------------------------------------------------------
__global__ __launch_bounds__(512, 2) void k_nw(const float* __restrict__ thD,
                                               const float* __restrict__ Aarr,
                                               uint32_t* __restrict__ po,
                                               float* __restrict__ ews) {
  const int tid = threadIdx.x;
  const int wl = __builtin_amdgcn_readfirstlane(tid) >> 6;  // wave id, forced SGPR
  const int lane = tid & 63;
  __shared__ float Vring[8][256];     // slot(d)=(d-2)&127, copy at +128
  __shared__ float Ering[8][256];     // slot(d)=d&127, copy at +128
  __shared__ uint32_t Pring[8][256];  // slot(d)=d&127, copy at +128

  const int b = blockIdx.x;
  for (int k = tid; k < 2048; k += 512) {
    ((float*)Vring)[k] = NEGF;
    ((float*)Ering)[k] = 0.0f;
    ((uint32_t*)Pring)[k] = 0u;
  }
  const float A2 = Aarr[b];
  const int r = 64 * wl + lane + 1;
  const bool lane0 = (lane == 0), lane63 = (lane == 63);
  const bool wgt0 = (wl > 0), wlt7 = (wl < 7);
  const bool rless = (r < 512);
  po += (size_t)b * NCELL;
  ews += (size_t)b * NCELL;
  thD += (size_t)b * NCELL;
  __syncthreads();

  // ================= forward =================
  const int ivLoF = 5 * wl;
  const int ivHiF = (5 * wl + 35 < NIV - 1) ? 5 * wl + 35 : NIV - 1;
  const int dnP0 = 2 + 64 * wl;  // dn0 at ivLoF

#define DECLTH(m) float th##m, thn##m;
  REP16(DECLTH)
#define PROTH(m) th##m = thD[dbase(dnP0 + (m)) + r];
  REP16(PROTH)
#define DECLST(m) float st##m;
  REP16(DECLST)

  float va = NEGF, rupP = NEGF;
#pragma unroll 1
  for (int iv = 0; iv < NIV; ++iv) {
    if (iv >= ivLoF && iv <= ivHiF) {
      const int dn0 = 2 - 16 * wl + 16 * iv;  // scalar
      const int s0 = (dn0 - 2) & 127;        // multiple of 16
      const int A = (s0 == 0) ? 124 : s0 - 4;
      const float* VrB = &Vring[wl][A];
      const float4 F0 = *(const float4*)&VrB[0];
      const float4 F1 = *(const float4*)&VrB[4];
      const float4 F2 = *(const float4*)&VrB[8];
      const float4 F3 = *(const float4*)&VrB[12];
      const float4 F4 = *(const float4*)&VrB[16];
      // issue next-interval theta loads (in flight across BAR)
      if (iv < ivHiF) {
        const int dnn0 = dn0 + 16;
#define LTHN(m) thn##m = thD[dbase(dnn0 + (m)) + r];
        REP16(LTHN)
      }

#define FSTEP(m, RVC) { \
    const int dn = dn0 + (m); \
    float rdg = rupP; \
    if ((m) == 0 && wl == 0 && iv == 0) rdg = lane0 ? 0.0f : rdg; /* V[0,0]=0 corner */ \
    const float rup = dpp_shr1_f(va, (RVC)); \
    float nv; uint32_t pk; \
    fcell(nv, pk, rdg, rup, va, th##m, A2); \
    const bool vv = (unsigned)(dn - r - 1) < 512u; \
    nv = vv ? nv : NEGF; \
    if (vv) po[dbase(dn) + r] = pk; \
    st##m = nv; \
    va = nv; rupP = rup; \
  }
      FSTEP(0, F0.w)  FSTEP(1, F1.x)  FSTEP(2, F1.y)  FSTEP(3, F1.z)  FSTEP(4, F1.w)
      FSTEP(5, F2.x)  FSTEP(6, F2.y)  FSTEP(7, F2.z)  FSTEP(8, F2.w)
      FSTEP(9, F3.x)  FSTEP(10, F3.y) FSTEP(11, F3.z) FSTEP(12, F3.w)
      FSTEP(13, F4.x) FSTEP(14, F4.y) FSTEP(15, F4.z)

      if (wlt7 && lane63) {  // batched boundary publish: diags [dn0, dn0+15]
        float* Wp_ = &Vring[wl + 1][s0];
        *(float4*)&Wp_[0] = make_float4(st0, st1, st2, st3);
        *(float4*)&Wp_[4] = make_float4(st4, st5, st6, st7);
        *(float4*)&Wp_[8] = make_float4(st8, st9, st10, st11);
        *(float4*)&Wp_[12] = make_float4(st12, st13, st14, st15);
        *(float4*)&Wp_[128] = make_float4(st0, st1, st2, st3);
        *(float4*)&Wp_[132] = make_float4(st4, st5, st6, st7);
        *(float4*)&Wp_[136] = make_float4(st8, st9, st10, st11);
        *(float4*)&Wp_[140] = make_float4(st12, st13, st14, st15);
      }
      // roll theta pipeline
      if (iv < ivHiF) {
#define THMV(m) th##m = thn##m;
        REP16(THMV)
      }
    }
    BAR();
  }

  // ================= transition: drain p stores once =================
  asm volatile("s_waitcnt vmcnt(0)" ::: "memory");
  __threadfence_block();
  __syncthreads();

  // ================= backward =================
  const float inv16 = 1.0f / 65535.0f;
  const bool w7 = (wl == 7);
  const int ivLoB = (34 - 5 * wl > 0) ? 34 - 5 * wl : 0;
  const int ivHiB = 70 - 5 * wl;
  float ea = (w7 && lane63) ? 1.0f : 0.0f;
  float reaP = 0.0f;
  uint32_t rqP = 0u;
  if (w7 && lane63) ews[NCELL - 1] = 1.0f;  // E(512,512) seed (diag 1024)

#define DECLQ(k) uint32_t q##k, qn##k;
  REP18(DECLQ)
  {
    const int t0p = 1135 - 16 * wl - 16 * ivLoB;
#define QLD0(k) q##k = po[dbase(t0p + 2 - (k)) + r];
    REP18(QLD0)
  }

#pragma unroll 1
  for (int iv = 0; iv < NIV; ++iv) {
    if (iv >= ivLoB && iv <= ivHiB) {
      const int t0 = 1135 - 16 * wl - 16 * iv;  // scalar; t0 % 16 == 15
      const int eb = (t0 - 15) & 127;           // multiple of 16
      const float* ErB = &Ering[wl][eb];
      const uint32_t* PrB = &Pring[wl][eb];
      const float4 G0 = *(const float4*)&ErB[0];
      const float4 G1 = *(const float4*)&ErB[4];
      const float4 G2 = *(const float4*)&ErB[8];
      const float4 G3 = *(const float4*)&ErB[12];
      const float4 G4 = *(const float4*)&ErB[16];
      const uint4 P0 = *(const uint4*)&PrB[0];
      const uint4 P1 = *(const uint4*)&PrB[4];
      const uint4 P2 = *(const uint4*)&PrB[8];
      const uint4 P3 = *(const uint4*)&PrB[12];
      const uint4 P4 = *(const uint4*)&PrB[16];
      // issue next-interval p loads (stay in flight across BAR)
      if (iv < ivHiB) {
        const int t0n = t0 - 16;
#define QLDN(k) qn##k = po[dbase(t0n + 2 - (k)) + r];
        REP18(QLDN)
      }
#define DECLSE(m) float stE##m;
      REP16(DECLSE)

#define BSTEP(m, QK, REC, RPC) { \
    const int t = t0 - (m); \
    const float reb = reaP; \
    const float rea = dpp_shl1_f(ea, (REC)); \
    const uint32_t rq2 = rqP; \
    const uint32_t rq1 = dpp_shl1_u((QK), (RPC)); \
    const bool vd = (unsigned)(t - r - 1) < 512u; \
    const bool rt = (unsigned)(t - r) < 512u; \
    const float pd = (float)(rq2 & 0xffffu) * inv16; \
    const float pu = (float)(rq1 >> 16) * inv16; \
    const float pl = 1.0f - (float)((QK) & 0xffffu) * inv16 - (float)((QK) >> 16) * inv16; \
    float n = (rless ? rea * pu : 0.0f) + ((rless && rt) ? reb * pd : 0.0f) + (rt ? ea * pl : 0.0f); \
    n = vd ? n : 0.0f; \
    if (vd) ews[dbase(t) + r] = n; \
    stE##m = n; \
    ea = n; reaP = rea; rqP = rq1; \
  }
      BSTEP(0, q1, G4.x, P4.x)  BSTEP(1, q2, G3.w, P3.w)  BSTEP(2, q3, G3.z, P3.z)
      BSTEP(3, q4, G3.y, P3.y)  BSTEP(4, q5, G3.x, P3.x)  BSTEP(5, q6, G2.w, P2.w)
      BSTEP(6, q7, G2.z, P2.z)  BSTEP(7, q8, G2.y, P2.y)  BSTEP(8, q9, G2.x, P2.x)
      BSTEP(9, q10, G1.w, P1.w) BSTEP(10, q11, G1.z, P1.z) BSTEP(11, q12, G1.y, P1.y)
      BSTEP(12, q13, G1.x, P1.x) BSTEP(13, q14, G0.w, P0.w) BSTEP(14, q15, G0.z, P0.z)
      BSTEP(15, q16, G0.y, P0.y)

      if (wgt0 && lane0) {  // batched publish: E diags [t0-15,t0], P diags [t0-15,t0+2] (+pad)
        float* We_ = &Ering[wl - 1][eb];
        *(float4*)&We_[0] = make_float4(stE15, stE14, stE13, stE12);
        *(float4*)&We_[4] = make_float4(stE11, stE10, stE9, stE8);
        *(float4*)&We_[8] = make_float4(stE7, stE6, stE5, stE4);
        *(float4*)&We_[12] = make_float4(stE3, stE2, stE1, stE0);
        *(float4*)&We_[128] = make_float4(stE15, stE14, stE13, stE12);
        *(float4*)&We_[132] = make_float4(stE11, stE10, stE9, stE8);
        *(float4*)&We_[136] = make_float4(stE7, stE6, stE5, stE4);
        *(float4*)&We_[140] = make_float4(stE3, stE2, stE1, stE0);
        uint32_t* Pw_ = &Pring[wl - 1][eb];
        *(uint4*)&Pw_[0] = make_uint4(q17, q16, q15, q14);
        *(uint4*)&Pw_[4] = make_uint4(q13, q12, q11, q10);
        *(uint4*)&Pw_[8] = make_uint4(q9, q8, q7, q6);
        *(uint4*)&Pw_[12] = make_uint4(q5, q4, q3, q2);
        *(uint4*)&Pw_[16] = make_uint4(q1, q0, q0, q0);
        *(uint4*)&Pw_[128] = make_uint4(q17, q16, q15, q14);
        *(uint4*)&Pw_[132] = make_uint4(q13, q12, q11, q10);
        *(uint4*)&Pw_[136] = make_uint4(q9, q8, q7, q6);
        *(uint4*)&Pw_[140] = make_uint4(q5, q4, q3, q2);
        *(uint4*)&Pw_[144] = make_uint4(q1, q0, q0, q0);
      }
      // roll pipelined q
      if (iv < ivHiB) {
#define QMV(k) q##k = qn##k;
        REP18(QMV)
      }
    }
    BAR();
  }
}

// ---------------------------------------------------------------------------
// K5: transpose diag-major E (ws) -> row-major out. 64x64 cell tiles.
// ---------------------------------------------------------------------------
__global__ __launch_bounds__(256) void k_tr(const float* __restrict__ ews, float* __restrict__ out) {
  const int blk = blockIdx.x;
  const int b = blk >> 6, ti = (blk >> 3) & 7, tj = blk & 7;
  const float* src = ews + (size_t)b * NCELL;
  float* dst = out + (size_t)b * NCELL;
  __shared__ float tile[64][68];
  const int i0 = ti * 64, j0 = tj * 64;
  const int t = threadIdx.x;
  const int sub = t >> 6, lane = t & 63;
  for (int k = sub; k < 127; k += 4) {
    const int d = i0 + j0 + 2 + k;
    const int ilo_t = max(i0 + 1, d - (j0 + 64));
    const int ihi_t = min(i0 + 64, d - (j0 + 1));
    const int i = ilo_t + lane;
    if (i <= ihi_t) {
      const int lo = (d > 513) ? d - 512 : 1;
      tile[i - 1 - i0][d - i - 1 - j0] = src[offd(d) - lo + i];
    }
  }
  __syncthreads();
  const int rr = t >> 2, q = (t & 3) * 16;
  float4* drow = (float4*)&dst[(size_t)(i0 + rr) * 512 + j0 + q];
  const float* srow = &tile[rr][q];
  drow[0] = *(const float4*)&srow[0];
  drow[1] = *(const float4*)&srow[4];
  drow[2] = *(const float4*)&srow[8];
  drow[3] = *(const float4*)&srow[12];
}

// ---------------------------------------------------------------------------
extern "C" void kernel_launch(void* const* d_in, const int* in_sizes, int n_in,
                              void* d_out, int out_size, void* d_ws, size_t ws_size,
                              hipStream_t stream) {
  const int* x = (const int*)d_in[0];
  const int* y = (const int*)d_in[1];
  const float* We = (const float*)d_in[2];
  const float* Wp = (const float*)d_in[3];
  const float* bp = (const float*)d_in[4];
  const float* Wg = (const float*)d_in[5];
  const float* bg = (const float*)d_in[6];
  float* out = (float*)d_out;

  float* ws = (float*)d_ws;
  float* T = ws;              // 22*512 floats
  float* G = ws + 11264;      // 814 (22x37 padded)
  float* u = G + 814;         // 22
  float* v = u + 22;          // 22
  float* A = v + 22;          // 16
  // 16 MiB region at +1 MiB: holds theta (diag-major) during forward,
  // overwritten by E (diag-major) during backward, read by k_tr.
  float* ews = (float*)((char*)d_ws + (1 << 20));

  k_T<<<22, 512, 0, stream>>>(We, Wp, bp, T);
  k_G<<<1, 512, 0, stream>>>(T, Wg, G, u, v);
  k_A<<<16, 256, 0, stream>>>(x, y, u, v, bg, A);
  k_th<<<128, 512, 0, stream>>>(x, y, G, ews);
  k_nw<<<16, 512, 0, stream>>>(ews, A, (uint32_t*)d_out, ews);
  k_tr<<<16 * 64, 256, 0, stream>>>(ews, out);
}

// Round 15
// 458.848 us; speedup vs baseline: 1.2014x; 1.2014x over previous
//
#include <hip/hip_runtime.h>
#include <stdint.h>

#define NEGF (-1.0e8f)
#define NCELL (512 * 512)
#define INVLN2 1.4426950408889634f
#define NIV 71  // intervals of 16 diagonals; skew 16/wave

// raw barrier: LDS ordering only (never drains vmcnt -> global ops stay in flight)
#define BAR() asm volatile("s_waitcnt lgkmcnt(0)\n\ts_barrier" ::: "memory")

#define REP16(X) X(0) X(1) X(2) X(3) X(4) X(5) X(6) X(7) X(8) X(9) X(10) X(11) X(12) X(13) X(14) X(15)
#define REP18(X) REP16(X) X(16) X(17)

__device__ __forceinline__ float exp2f_(float x) {
#if __has_builtin(__builtin_amdgcn_exp2f)
  return __builtin_amdgcn_exp2f(x);
#else
  return exp2f(x);
#endif
}
__device__ __forceinline__ float log2f_(float x) {
#if __has_builtin(__builtin_amdgcn_logf)
  return __builtin_amdgcn_logf(x);
#else
  return log2f(x);
#endif
}
__device__ __forceinline__ uint32_t pknorm16(float a, float b) {
#if __has_builtin(__builtin_amdgcn_cvt_pknorm_u16)
  typedef unsigned short u2v __attribute__((ext_vector_type(2)));
  union { u2v v; uint32_t u; } cv;
  cv.v = __builtin_amdgcn_cvt_pknorm_u16(a, b);
  return cv.u;
#else
  uint32_t pa = (uint32_t)(a * 65535.0f + 0.5f);
  uint32_t pb = (uint32_t)(b * 65535.0f + 0.5f);
  return pa | (pb << 16);
#endif
}

// DPP wave shifts: 0x138 wave_shr:1 (lane l <- l-1, lane0 <- old), 0x130 wave_shl:1 (lane l <- l+1, lane63 <- old)
__device__ __forceinline__ float dpp_shr1_f(float src, float old0) {
  return __int_as_float(__builtin_amdgcn_update_dpp(
      __float_as_int(old0), __float_as_int(src), 0x138, 0xF, 0xF, false));
}
__device__ __forceinline__ float dpp_shl1_f(float src, float old63) {
  return __int_as_float(__builtin_amdgcn_update_dpp(
      __float_as_int(old63), __float_as_int(src), 0x130, 0xF, 0xF, false));
}
__device__ __forceinline__ uint32_t dpp_shl1_u(uint32_t src, uint32_t old63) {
  return (uint32_t)__builtin_amdgcn_update_dpp((int)old63, (int)src, 0x130, 0xF, 0xF, false);
}

// offset of diagonal d; lo(d)=max(1,d-512)
__device__ __forceinline__ int offd(int d) {
  return (d <= 513) ? (((d - 2) * (d - 1)) >> 1)
                    : (NCELL - (((1025 - d) * (1026 - d)) >> 1));
}
__device__ __forceinline__ int dbase(int d) {
  const int lo = (d > 513) ? d - 512 : 1;
  return offd(d) - lo;
}

// forward softmax-LSE cell (base-2 domain)
__device__ __forceinline__ void fcell(float& nv, uint32_t& pk, float dg, float up0,
                                      float lf0, float th, float A2) {
  float up = up0 + A2, lf = lf0 + A2;
  float mx = fmaxf(fmaxf(dg, up), lf);
  float ed = exp2f_(dg - mx), eu = exp2f_(up - mx), el = exp2f_(lf - mx);
  float s = ed + eu + el;
  nv = th + mx + log2f_(s);
  float rs = __builtin_amdgcn_rcpf(s);
  pk = pknorm16(ed * rs, eu * rs);
}

// ---------------------------------------------------------------------------
// K1: T[22][512] = W_embed @ W_proj + b_proj
// ---------------------------------------------------------------------------
__global__ void k_T(const float* __restrict__ We, const float* __restrict__ Wp,
                    const float* __restrict__ bp, float* __restrict__ T) {
  int a = blockIdx.x, c = threadIdx.x;
  __shared__ float e[512];
  e[c] = We[a * 512 + c];
  __syncthreads();
  float acc = bp[c];
#pragma unroll 8
  for (int k = 0; k < 512; ++k) acc = fmaf(e[k], Wp[k * 512 + c], acc);
  T[a * 512 + c] = acc;
}

// ---------------------------------------------------------------------------
// K2 (parallelized): block a computes G2[a][0..21] (stride 37), u[a], v[a].
//     Each wave owns reductions j = wv, wv+8, wv+16 (shuffle-reduce over 64).
// ---------------------------------------------------------------------------
__global__ __launch_bounds__(512) void k_G(const float* __restrict__ T, const float* __restrict__ Wg,
                                           float* __restrict__ G, float* __restrict__ u,
                                           float* __restrict__ v) {
  const int a = blockIdx.x;  // 22 blocks
  const int tid = threadIdx.x;
  const int wv = tid >> 6, lane = tid & 63;
  __shared__ float Ta[512];
  Ta[tid] = T[a * 512 + tid];
  __syncthreads();
  for (int j = wv; j < 24; j += 8) {
    const float* src = (j < 22) ? &T[j * 512] : &Wg[(j - 22) * 512];
    float s = 0.f;
#pragma unroll
    for (int c0 = 0; c0 < 512; c0 += 64) s = fmaf(Ta[c0 + lane], src[c0 + lane], s);
    for (int o = 32; o > 0; o >>= 1) s += __shfl_down(s, o, 64);
    if (lane == 0) {
      if (j < 22) G[a * 37 + j] = s * INVLN2;
      else if (j == 22) u[a] = s;
      else v[a] = s;
    }
  }
}

// ---------------------------------------------------------------------------
// K3: A2[b]
// ---------------------------------------------------------------------------
__global__ void k_A(const int* __restrict__ x, const int* __restrict__ y,
                    const float* __restrict__ u, const float* __restrict__ v,
                    const float* __restrict__ bg, float* __restrict__ A) {
  int b = blockIdx.x, t = threadIdx.x;
  const int* xb = x + b * 512;
  const int* yb = y + b * 512;
  float s = u[xb[t]] + u[xb[t + 256]] + v[yb[t]] + v[yb[t + 256]];
  for (int o = 32; o > 0; o >>= 1) s += __shfl_down(s, o, 64);
  __shared__ float w[4];
  if ((t & 63) == 0) w[t >> 6] = s;
  __syncthreads();
  if (t == 0) A[b] = ((w[0] + w[1] + w[2] + w[3]) * (1.0f / 512.0f) + bg[0]) * INVLN2;
}

// ---------------------------------------------------------------------------
// K4: skewed 8-wave pipeline DP, KD=16, gating, LDS-instruction-minimized:
//     ring reads via 5x ds_read_b128, ring writes batched (stash->b128x4 x2).
//     (round-13 proven-best configuration)
// ---------------------------------------------------------------------------
__global__ __launch_bounds__(512) void k_nw(const int* __restrict__ x, const int* __restrict__ y,
                                            const float* __restrict__ G,
                                            const float* __restrict__ Aarr,
                                            uint32_t* __restrict__ po,
                                            float* __restrict__ ews) {
  const int tid = threadIdx.x;
  const int wl = __builtin_amdgcn_readfirstlane(tid) >> 6;  // wave id, forced SGPR
  const int lane = tid & 63;
  __shared__ float Gl[814];       // 22 x 37
  __shared__ int ysPad[1856];     // zeros [0,640), ys [640,1152), zeros [1152,1856)
  __shared__ float Vring[8][256];     // slot(d)=(d-2)&127, copy at +128
  __shared__ float Ering[8][256];     // slot(d)=d&127, copy at +128
  __shared__ uint32_t Pring[8][256];  // slot(d)=d&127, copy at +128

  const int b = blockIdx.x;
  const int* xbp = x + b * 512;
  const int* ybp = y + b * 512;
  for (int k = tid; k < 640; k += 512) ysPad[k] = 0;
  for (int k = 1152 + tid; k < 1856; k += 512) ysPad[k] = 0;
  ysPad[640 + tid] = ybp[tid];
  for (int k = tid; k < 814; k += 512) Gl[k] = G[k];
  for (int k = tid; k < 2048; k += 512) {
    ((float*)Vring)[k] = NEGF;
    ((float*)Ering)[k] = 0.0f;
    ((uint32_t*)Pring)[k] = 0u;
  }
  const float A2 = Aarr[b];
  const int r = 64 * wl + lane + 1;
  const int xr = xbp[r - 1] * 37;
  const bool lane0 = (lane == 0), lane63 = (lane == 63);
  const bool wgt0 = (wl > 0), wlt7 = (wl < 7);
  const bool rless = (r < 512);
  po += (size_t)b * NCELL;
  ews += (size_t)b * NCELL;
  __syncthreads();

  // ================= forward =================
  const int ivLoF = 5 * wl;
  const int ivHiF = (5 * wl + 35 < NIV - 1) ? 5 * wl + 35 : NIV - 1;
  const int dnP0 = 2 + 64 * wl;  // dn0 at ivLoF

#define DECLTH(m) float th##m;
  REP16(DECLTH)
#define DECLYA(m) int ya##m;
  REP16(DECLYA)
#define PROTH(m) { const int ix = (dnP0 + (m)) + 639 - r; th##m = Gl[xr + ysPad[ix]]; }
  REP16(PROTH)

  float va = NEGF, rupP = NEGF;
#pragma unroll 1
  for (int iv = 0; iv < NIV; ++iv) {
    if (iv >= ivLoF && iv <= ivHiF) {
      const int dn0 = 2 - 16 * wl + 16 * iv;  // scalar
      const int s0 = (dn0 - 2) & 127;        // multiple of 16
      const int A = (s0 == 0) ? 124 : s0 - 4;
      const float* VrB = &Vring[wl][A];
      const float4 F0 = *(const float4*)&VrB[0];
      const float4 F1 = *(const float4*)&VrB[4];
      const float4 F2 = *(const float4*)&VrB[8];
      const float4 F3 = *(const float4*)&VrB[12];
      const float4 F4 = *(const float4*)&VrB[16];
      // batch-load next interval's ys into registers (stride-1, conflict-light)
      const int iya = dn0 + 655 - r;
#define LYA(m) ya##m = ysPad[iya + (m)];
      REP16(LYA)
#define DECLST(m) float st##m;
      REP16(DECLST)

#define FSTEP(m, RVC) { \
    const int dn = dn0 + (m); \
    float rdg = rupP; \
    if ((m) == 0 && wl == 0 && iv == 0) rdg = lane0 ? 0.0f : rdg; /* V[0,0]=0 corner */ \
    const float rup = dpp_shr1_f(va, (RVC)); \
    float nv; uint32_t pk; \
    fcell(nv, pk, rdg, rup, va, th##m, A2); \
    const bool vv = (unsigned)(dn - r - 1) < 512u; \
    nv = vv ? nv : NEGF; \
    if (vv) po[dbase(dn) + r] = pk; \
    st##m = nv; \
    th##m = Gl[xr + ya##m]; \
    va = nv; rupP = rup; \
  }
      FSTEP(0, F0.w)  FSTEP(1, F1.x)  FSTEP(2, F1.y)  FSTEP(3, F1.z)  FSTEP(4, F1.w)
      FSTEP(5, F2.x)  FSTEP(6, F2.y)  FSTEP(7, F2.z)  FSTEP(8, F2.w)
      FSTEP(9, F3.x)  FSTEP(10, F3.y) FSTEP(11, F3.z) FSTEP(12, F3.w)
      FSTEP(13, F4.x) FSTEP(14, F4.y) FSTEP(15, F4.z)

      if (wlt7 && lane63) {  // batched boundary publish: diags [dn0, dn0+15]
        float* Wp_ = &Vring[wl + 1][s0];
        *(float4*)&Wp_[0] = make_float4(st0, st1, st2, st3);
        *(float4*)&Wp_[4] = make_float4(st4, st5, st6, st7);
        *(float4*)&Wp_[8] = make_float4(st8, st9, st10, st11);
        *(float4*)&Wp_[12] = make_float4(st12, st13, st14, st15);
        *(float4*)&Wp_[128] = make_float4(st0, st1, st2, st3);
        *(float4*)&Wp_[132] = make_float4(st4, st5, st6, st7);
        *(float4*)&Wp_[136] = make_float4(st8, st9, st10, st11);
        *(float4*)&Wp_[140] = make_float4(st12, st13, st14, st15);
      }
    }
    BAR();
  }

  // ================= transition: drain p stores once =================
  asm volatile("s_waitcnt vmcnt(0)" ::: "memory");
  __threadfence_block();
  __syncthreads();

  // ================= backward =================
  const float inv16 = 1.0f / 65535.0f;
  const bool w7 = (wl == 7);
  const int ivLoB = (34 - 5 * wl > 0) ? 34 - 5 * wl : 0;
  const int ivHiB = 70 - 5 * wl;
  float ea = (w7 && lane63) ? 1.0f : 0.0f;
  float reaP = 0.0f;
  uint32_t rqP = 0u;
  if (w7 && lane63) ews[NCELL - 1] = 1.0f;  // E(512,512) seed (diag 1024)

#define DECLQ(k) uint32_t q##k, qn##k;
  REP18(DECLQ)
  {
    const int t0p = 1135 - 16 * wl - 16 * ivLoB;
#define QLD0(k) q##k = po[dbase(t0p + 2 - (k)) + r];
    REP18(QLD0)
  }

#pragma unroll 1
  for (int iv = 0; iv < NIV; ++iv) {
    if (iv >= ivLoB && iv <= ivHiB) {
      const int t0 = 1135 - 16 * wl - 16 * iv;  // scalar; t0 % 16 == 15
      const int eb = (t0 - 15) & 127;           // multiple of 16
      const float* ErB = &Ering[wl][eb];
      const uint32_t* PrB = &Pring[wl][eb];
      const float4 G0 = *(const float4*)&ErB[0];
      const float4 G1 = *(const float4*)&ErB[4];
      const float4 G2 = *(const float4*)&ErB[8];
      const float4 G3 = *(const float4*)&ErB[12];
      const float4 G4 = *(const float4*)&ErB[16];
      const uint4 P0 = *(const uint4*)&PrB[0];
      const uint4 P1 = *(const uint4*)&PrB[4];
      const uint4 P2 = *(const uint4*)&PrB[8];
      const uint4 P3 = *(const uint4*)&PrB[12];
      const uint4 P4 = *(const uint4*)&PrB[16];
      // issue next-interval p loads (stay in flight across BAR)
      if (iv < ivHiB) {
        const int t0n = t0 - 16;
#define QLDN(k) qn##k = po[dbase(t0n + 2 - (k)) + r];
        REP18(QLDN)
      }
#define DECLSE(m) float stE##m;
      REP16(DECLSE)

#define BSTEP(m, QK, REC, RPC) { \
    const int t = t0 - (m); \
    const float reb = reaP; \
    const float rea = dpp_shl1_f(ea, (REC)); \
    const uint32_t rq2 = rqP; \
    const uint32_t rq1 = dpp_shl1_u((QK), (RPC)); \
    const bool vd = (unsigned)(t - r - 1) < 512u; \
    const bool rt = (unsigned)(t - r) < 512u; \
    const float pd = (float)(rq2 & 0xffffu) * inv16; \
    const float pu = (float)(rq1 >> 16) * inv16; \
    const float pl = 1.0f - (float)((QK) & 0xffffu) * inv16 - (float)((QK) >> 16) * inv16; \
    float n = (rless ? rea * pu : 0.0f) + ((rless && rt) ? reb * pd : 0.0f) + (rt ? ea * pl : 0.0f); \
    n = vd ? n : 0.0f; \
    if (vd) ews[dbase(t) + r] = n; \
    stE##m = n; \
    ea = n; reaP = rea; rqP = rq1; \
  }
      BSTEP(0, q1, G4.x, P4.x)  BSTEP(1, q2, G3.w, P3.w)  BSTEP(2, q3, G3.z, P3.z)
      BSTEP(3, q4, G3.y, P3.y)  BSTEP(4, q5, G3.x, P3.x)  BSTEP(5, q6, G2.w, P2.w)
      BSTEP(6, q7, G2.z, P2.z)  BSTEP(7, q8, G2.y, P2.y)  BSTEP(8, q9, G2.x, P2.x)
      BSTEP(9, q10, G1.w, P1.w) BSTEP(10, q11, G1.z, P1.z) BSTEP(11, q12, G1.y, P1.y)
      BSTEP(12, q13, G1.x, P1.x) BSTEP(13, q14, G0.w, P0.w) BSTEP(14, q15, G0.z, P0.z)
      BSTEP(15, q16, G0.y, P0.y)

      if (wgt0 && lane0) {  // batched publish: E diags [t0-15,t0], P diags [t0-15,t0+2] (+pad)
        float* We_ = &Ering[wl - 1][eb];
        *(float4*)&We_[0] = make_float4(stE15, stE14, stE13, stE12);
        *(float4*)&We_[4] = make_float4(stE11, stE10, stE9, stE8);
        *(float4*)&We_[8] = make_float4(stE7, stE6, stE5, stE4);
        *(float4*)&We_[12] = make_float4(stE3, stE2, stE1, stE0);
        *(float4*)&We_[128] = make_float4(stE15, stE14, stE13, stE12);
        *(float4*)&We_[132] = make_float4(stE11, stE10, stE9, stE8);
        *(float4*)&We_[136] = make_float4(stE7, stE6, stE5, stE4);
        *(float4*)&We_[140] = make_float4(stE3, stE2, stE1, stE0);
        uint32_t* Pw_ = &Pring[wl - 1][eb];
        *(uint4*)&Pw_[0] = make_uint4(q17, q16, q15, q14);
        *(uint4*)&Pw_[4] = make_uint4(q13, q12, q11, q10);
        *(uint4*)&Pw_[8] = make_uint4(q9, q8, q7, q6);
        *(uint4*)&Pw_[12] = make_uint4(q5, q4, q3, q2);
        *(uint4*)&Pw_[16] = make_uint4(q1, q0, q0, q0);
        *(uint4*)&Pw_[128] = make_uint4(q17, q16, q15, q14);
        *(uint4*)&Pw_[132] = make_uint4(q13, q12, q11, q10);
        *(uint4*)&Pw_[136] = make_uint4(q9, q8, q7, q6);
        *(uint4*)&Pw_[140] = make_uint4(q5, q4, q3, q2);
        *(uint4*)&Pw_[144] = make_uint4(q1, q0, q0, q0);
      }
      // roll pipelined q
      if (iv < ivHiB) {
#define QMV(k) q##k = qn##k;
        REP18(QMV)
      }
    }
    BAR();
  }
}

// ---------------------------------------------------------------------------
// K5: transpose diag-major E (ws) -> row-major out. 64x64 cell tiles.
// ---------------------------------------------------------------------------
__global__ __launch_bounds__(256) void k_tr(const float* __restrict__ ews, float* __restrict__ out) {
  const int blk = blockIdx.x;
  const int b = blk >> 6, ti = (blk >> 3) & 7, tj = blk & 7;
  const float* src = ews + (size_t)b * NCELL;
  float* dst = out + (size_t)b * NCELL;
  __shared__ float tile[64][68];
  const int i0 = ti * 64, j0 = tj * 64;
  const int t = threadIdx.x;
  const int sub = t >> 6, lane = t & 63;
  for (int k = sub; k < 127; k += 4) {
    const int d = i0 + j0 + 2 + k;
    const int ilo_t = max(i0 + 1, d - (j0 + 64));
    const int ihi_t = min(i0 + 64, d - (j0 + 1));
    const int i = ilo_t + lane;
    if (i <= ihi_t) {
      const int lo = (d > 513) ? d - 512 : 1;
      tile[i - 1 - i0][d - i - 1 - j0] = src[offd(d) - lo + i];
    }
  }
  __syncthreads();
  const int rr = t >> 2, q = (t & 3) * 16;
  float4* drow = (float4*)&dst[(size_t)(i0 + rr) * 512 + j0 + q];
  const float* srow = &tile[rr][q];
  drow[0] = *(const float4*)&srow[0];
  drow[1] = *(const float4*)&srow[4];
  drow[2] = *(const float4*)&srow[8];
  drow[3] = *(const float4*)&srow[12];
}

// ---------------------------------------------------------------------------
extern "C" void kernel_launch(void* const* d_in, const int* in_sizes, int n_in,
                              void* d_out, int out_size, void* d_ws, size_t ws_size,
                              hipStream_t stream) {
  const int* x = (const int*)d_in[0];
  const int* y = (const int*)d_in[1];
  const float* We = (const float*)d_in[2];
  const float* Wp = (const float*)d_in[3];
  const float* bp = (const float*)d_in[4];
  const float* Wg = (const float*)d_in[5];
  const float* bg = (const float*)d_in[6];
  float* out = (float*)d_out;

  float* ws = (float*)d_ws;
  float* T = ws;              // 22*512 floats
  float* G = ws + 11264;      // 814 (22x37 padded)
  float* u = G + 814;         // 22
  float* v = u + 22;          // 22
  float* A = v + 22;          // 16
  float* ews = (float*)((char*)d_ws + (1 << 20));  // 16 MiB diag-major E

  k_T<<<22, 512, 0, stream>>>(We, Wp, bp, T);
  k_G<<<22, 512, 0, stream>>>(T, Wg, G, u, v);
  k_A<<<16, 256, 0, stream>>>(x, y, u, v, bg, A);
  k_nw<<<16, 512, 0, stream>>>(x, y, G, A, (uint32_t*)d_out, ews);
  k_tr<<<16 * 64, 256, 0, stream>>>(ews, out);
}

// Round 17
// 289.557 us; speedup vs baseline: 1.9038x; 1.5847x over previous
//
#include <hip/hip_runtime.h>
#include <stdint.h>

#define NEGF (-1.0e8f)
#define NCELL (512 * 512)
#define INVLN2 1.4426950408889634f
#define NIV 71  // intervals of 16 diagonals; skew 16/wave

// raw barrier: LDS ordering only (never drains vmcnt -> global ops stay in flight)
#define BAR() asm volatile("s_waitcnt lgkmcnt(0)\n\ts_barrier" ::: "memory")

#define REP16(X) X(0) X(1) X(2) X(3) X(4) X(5) X(6) X(7) X(8) X(9) X(10) X(11) X(12) X(13) X(14) X(15)

__device__ __forceinline__ float exp2f_(float x) {
#if __has_builtin(__builtin_amdgcn_exp2f)
  return __builtin_amdgcn_exp2f(x);
#else
  return exp2f(x);
#endif
}
__device__ __forceinline__ float log2f_(float x) {
#if __has_builtin(__builtin_amdgcn_logf)
  return __builtin_amdgcn_logf(x);
#else
  return log2f(x);
#endif
}

// DPP wave shift: 0x138 wave_shr:1 (lane l <- l-1, lane0 <- old)
__device__ __forceinline__ float dpp_shr1_f(float src, float old0) {
  return __int_as_float(__builtin_amdgcn_update_dpp(
      __float_as_int(old0), __float_as_int(src), 0x138, 0xF, 0xF, false));
}

// offset of diagonal d; lo(d)=max(1,d-512)
__device__ __forceinline__ int offd(int d) {
  return (d <= 513) ? (((d - 2) * (d - 1)) >> 1)
                    : (NCELL - (((1025 - d) * (1026 - d)) >> 1));
}
__device__ __forceinline__ int dbase(int d) {
  const int lo = (d > 513) ? d - 512 : 1;
  return offd(d) - lo;
}

// forward softmax-LSE cell (base-2 domain): nv = th + lsev
__device__ __forceinline__ void fcellF(float& nv, float& lsev, float dg, float up0,
                                       float lf0, float th, float A2) {
  float up = up0 + A2, lf = lf0 + A2;
  float mx = fmaxf(fmaxf(dg, up), lf);
  float s = exp2f_(dg - mx) + exp2f_(up - mx) + exp2f_(lf - mx);
  lsev = mx + log2f_(s);
  nv = th + lsev;
}

// ---------------------------------------------------------------------------
// K1: T[22][512] = W_embed @ W_proj + b_proj
// ---------------------------------------------------------------------------
__global__ void k_T(const float* __restrict__ We, const float* __restrict__ Wp,
                    const float* __restrict__ bp, float* __restrict__ T) {
  int a = blockIdx.x, c = threadIdx.x;
  __shared__ float e[512];
  e[c] = We[a * 512 + c];
  __syncthreads();
  float acc = bp[c];
#pragma unroll 8
  for (int k = 0; k < 512; ++k) acc = fmaf(e[k], Wp[k * 512 + c], acc);
  T[a * 512 + c] = acc;
}

// ---------------------------------------------------------------------------
// K2 (parallelized): block a computes G2[a][0..21] (stride 37), u[a], v[a].
// ---------------------------------------------------------------------------
__global__ __launch_bounds__(512) void k_G(const float* __restrict__ T, const float* __restrict__ Wg,
                                           float* __restrict__ G, float* __restrict__ u,
                                           float* __restrict__ v) {
  const int a = blockIdx.x;  // 22 blocks
  const int tid = threadIdx.x;
  const int wv = tid >> 6, lane = tid & 63;
  __shared__ float Ta[512];
  Ta[tid] = T[a * 512 + tid];
  __syncthreads();
  for (int j = wv; j < 24; j += 8) {
    const float* src = (j < 22) ? &T[j * 512] : &Wg[(j - 22) * 512];
    float s = 0.f;
#pragma unroll
    for (int c0 = 0; c0 < 512; c0 += 64) s = fmaf(Ta[c0 + lane], src[c0 + lane], s);
    for (int o = 32; o > 0; o >>= 1) s += __shfl_down(s, o, 64);
    if (lane == 0) {
      if (j < 22) G[a * 37 + j] = s * INVLN2;
      else if (j == 22) u[a] = s;
      else v[a] = s;
    }
  }
}

// ---------------------------------------------------------------------------
// K3: A2[b]
// ---------------------------------------------------------------------------
__global__ void k_A(const int* __restrict__ x, const int* __restrict__ y,
                    const float* __restrict__ u, const float* __restrict__ v,
                    const float* __restrict__ bg, float* __restrict__ A) {
  int b = blockIdx.x, t = threadIdx.x;
  const int* xb = x + b * 512;
  const int* yb = y + b * 512;
  float s = u[xb[t]] + u[xb[t + 256]] + v[yb[t]] + v[yb[t + 256]];
  for (int o = 32; o > 0; o >>= 1) s += __shfl_down(s, o, 64);
  __shared__ float w[4];
  if ((t & 63) == 0) w[t >> 6] = s;
  __syncthreads();
  if (t == 0) A[b] = ((w[0] + w[1] + w[2] + w[3]) * (1.0f / 512.0f) + bg[0]) * INVLN2;
}

// ---------------------------------------------------------------------------
// K4: forward-only skewed 8-wave pipeline DP with wave-local re-centering.
//     32 blocks: block 2b   -> F sweep of batch b (stores full F, diag-major)
//                block 2b+1 -> suffix sweep on REVERSED x,y (stores lse-part
//                              = B[513-i',513-j'], rev diag-major).
//     E[i,j] = exp2(F[i,j] + B[i,j] - Ftot) computed later by k_E.
//     va carried offset-reduced (|f~| small); Off restored at stores/publish.
// ---------------------------------------------------------------------------
__global__ __launch_bounds__(512) void k_nw(const int* __restrict__ x, const int* __restrict__ y,
                                            const float* __restrict__ G,
                                            const float* __restrict__ Aarr,
                                            float* __restrict__ Fws,
                                            float* __restrict__ Gws,
                                            float* __restrict__ Ftots) {
  const int tid = threadIdx.x;
  const int wl = __builtin_amdgcn_readfirstlane(tid) >> 6;  // wave id, forced SGPR
  const int lane = tid & 63;
  __shared__ float Gl[814];       // 22 x 37
  __shared__ int ysPad[1856];     // zeros [0,640), ys [640,1152), zeros [1152,1856)
  __shared__ float Vring[8][256]; // slot(d)=(d-2)&127, copy at +128; ABSOLUTE values

  const int bb = blockIdx.x;
  const int b = bb >> 1;
  const bool rev = (bb & 1) != 0;
  const int* xbp = x + b * 512;
  const int* ybp = y + b * 512;
  for (int k = tid; k < 640; k += 512) ysPad[k] = 0;
  for (int k = 1152 + tid; k < 1856; k += 512) ysPad[k] = 0;
  ysPad[640 + tid] = ybp[rev ? 511 - tid : tid];
  for (int k = tid; k < 814; k += 512) Gl[k] = G[k];
  for (int k = tid; k < 2048; k += 512) ((float*)Vring)[k] = NEGF;
  const float A2 = Aarr[b];
  const int r = 64 * wl + lane + 1;
  const int xr = xbp[rev ? 512 - r : r - 1] * 37;
  const bool lane0 = (lane == 0), lane63 = (lane == 63);
  const bool wlt7 = (wl < 7);
  float* __restrict__ dst = (rev ? Gws : Fws) + (size_t)b * NCELL;
  __syncthreads();

  const int ivLoF = 5 * wl;
  const int ivHiF = (5 * wl + 35 < NIV - 1) ? 5 * wl + 35 : NIV - 1;
  const int dnP0 = 2 + 64 * wl;  // dn0 at ivLoF

#define DECLTH(m) float th##m;
  REP16(DECLTH)
#define DECLYA(m) int ya##m;
  REP16(DECLYA)
#define PROTH(m) { const int ix = (dnP0 + (m)) + 639 - r; th##m = Gl[xr + ysPad[ix]]; }
  REP16(PROTH)

  float va = NEGF, rupP = NEGF, Off = 0.0f;
#pragma unroll 1
  for (int iv = 0; iv < NIV; ++iv) {
    if (iv >= ivLoF && iv <= ivHiF) {
      // ---- re-center: subtract wave-uniform offset (lse shift-invariance) ----
      {
        float o = __int_as_float(__builtin_amdgcn_readfirstlane(__float_as_int(va)));
        o = (fabsf(o) < 1.0e7f) ? o : 0.0f;
        va -= o; rupP -= o; Off += o;
      }
      const int dn0 = 2 - 16 * wl + 16 * iv;  // scalar
      const int s0 = (dn0 - 2) & 127;        // multiple of 16
      const int A = (s0 == 0) ? 124 : s0 - 4;
      const float* VrB = &Vring[wl][A];
      float4 F0 = *(const float4*)&VrB[0];
      float4 F1 = *(const float4*)&VrB[4];
      float4 F2 = *(const float4*)&VrB[8];
      float4 F3 = *(const float4*)&VrB[12];
      float4 F4 = *(const float4*)&VrB[16];
      // ring holds ABSOLUTE values -> bring into local offset domain
#define SUBO(V) V.x -= Off; V.y -= Off; V.z -= Off; V.w -= Off;
      SUBO(F0) SUBO(F1) SUBO(F2) SUBO(F3) SUBO(F4)
      // batch-load next interval's ys into registers (stride-1)
      const int iya = dn0 + 655 - r;
#define LYA(m) ya##m = ysPad[iya + (m)];
      REP16(LYA)
#define DECLST(m) float st##m;
      REP16(DECLST)

#define FSTEP(m, RVC) { \
    const int dn = dn0 + (m); \
    float rdg = rupP; \
    if ((m) == 0 && wl == 0 && iv == 0) rdg = lane0 ? 0.0f : rdg; /* corner=0 */ \
    const float rup = dpp_shr1_f(va, (RVC)); \
    float nv, lsv; \
    fcellF(nv, lsv, rdg, rup, va, th##m, A2); \
    const bool vv = (unsigned)(dn - r - 1) < 512u; \
    if (vv) dst[dbase(dn) + r] = (rev ? lsv : nv) + Off; \
    if (!rev && dn == 1024 && r == 512) Ftots[b] = nv + Off; \
    nv = vv ? nv : NEGF; \
    st##m = nv; \
    th##m = Gl[xr + ya##m]; \
    va = nv; rupP = rup; \
  }
      FSTEP(0, F0.w)  FSTEP(1, F1.x)  FSTEP(2, F1.y)  FSTEP(3, F1.z)  FSTEP(4, F1.w)
      FSTEP(5, F2.x)  FSTEP(6, F2.y)  FSTEP(7, F2.z)  FSTEP(8, F2.w)
      FSTEP(9, F3.x)  FSTEP(10, F3.y) FSTEP(11, F3.z) FSTEP(12, F3.w)
      FSTEP(13, F4.x) FSTEP(14, F4.y) FSTEP(15, F4.z)

      if (wlt7 && lane63) {  // batched boundary publish (absolute): diags [dn0, dn0+15]
        const float4 S0 = make_float4(st0 + Off, st1 + Off, st2 + Off, st3 + Off);
        const float4 S1 = make_float4(st4 + Off, st5 + Off, st6 + Off, st7 + Off);
        const float4 S2 = make_float4(st8 + Off, st9 + Off, st10 + Off, st11 + Off);
        const float4 S3 = make_float4(st12 + Off, st13 + Off, st14 + Off, st15 + Off);
        float* Wp_ = &Vring[wl + 1][s0];
        *(float4*)&Wp_[0] = S0;
        *(float4*)&Wp_[4] = S1;
        *(float4*)&Wp_[8] = S2;
        *(float4*)&Wp_[12] = S3;
        *(float4*)&Wp_[128] = S0;
        *(float4*)&Wp_[132] = S1;
        *(float4*)&Wp_[136] = S2;
        *(float4*)&Wp_[140] = S3;
      }
    }
    BAR();
  }
}

// ---------------------------------------------------------------------------
// K4b: E = exp2(F + G - Ftot), in place over Fws (diag-major).
//      G[i,j] lives at rev-layout: d'=1026-d, i'=513-i.
//      128 blocks = 16 batches x 8 diag-segments; 512 threads.
// ---------------------------------------------------------------------------
__global__ __launch_bounds__(512) void k_E(const float* __restrict__ Gws,
                                           const float* __restrict__ Ftots,
                                           float* __restrict__ Fws) {
  const int blk = blockIdx.x;
  const int b = blk >> 3, seg = blk & 7;
  const int tid = threadIdx.x;
  const float* Gs = Gws + (size_t)b * NCELL;
  float* Fs = Fws + (size_t)b * NCELL;
  const float Ftot = Ftots[b];
  for (int d = 2 + seg; d <= 1024; d += 8) {
    const int lo = (d > 513) ? d - 512 : 1;
    const int hi = (d - 1 < 512) ? d - 1 : 512;
    const int i = lo + tid;
    if (i <= hi) {
      const int dp = 1026 - d, ip = 513 - i;
      const int lop = (dp > 513) ? dp - 512 : 1;
      const int sf = offd(d) - lo + i;
      const float F = Fs[sf];
      const float Gv = Gs[offd(dp) - lop + ip];
      Fs[sf] = exp2f_(F + Gv - Ftot);
    }
  }
}

// ---------------------------------------------------------------------------
// K5: transpose diag-major E (ws) -> row-major out. 64x64 cell tiles.
// ---------------------------------------------------------------------------
__global__ __launch_bounds__(256) void k_tr(const float* __restrict__ ews, float* __restrict__ out) {
  const int blk = blockIdx.x;
  const int b = blk >> 6, ti = (blk >> 3) & 7, tj = blk & 7;
  const float* src = ews + (size_t)b * NCELL;
  float* dst = out + (size_t)b * NCELL;
  __shared__ float tile[64][68];
  const int i0 = ti * 64, j0 = tj * 64;
  const int t = threadIdx.x;
  const int sub = t >> 6, lane = t & 63;
  for (int k = sub; k < 127; k += 4) {
    const int d = i0 + j0 + 2 + k;
    const int ilo_t = max(i0 + 1, d - (j0 + 64));
    const int ihi_t = min(i0 + 64, d - (j0 + 1));
    const int i = ilo_t + lane;
    if (i <= ihi_t) {
      const int lo = (d > 513) ? d - 512 : 1;
      tile[i - 1 - i0][d - i - 1 - j0] = src[offd(d) - lo + i];
    }
  }
  __syncthreads();
  const int rr = t >> 2, q = (t & 3) * 16;
  float4* drow = (float4*)&dst[(size_t)(i0 + rr) * 512 + j0 + q];
  const float* srow = &tile[rr][q];
  drow[0] = *(const float4*)&srow[0];
  drow[1] = *(const float4*)&srow[4];
  drow[2] = *(const float4*)&srow[8];
  drow[3] = *(const float4*)&srow[12];
}

// ---------------------------------------------------------------------------
extern "C" void kernel_launch(void* const* d_in, const int* in_sizes, int n_in,
                              void* d_out, int out_size, void* d_ws, size_t ws_size,
                              hipStream_t stream) {
  const int* x = (const int*)d_in[0];
  const int* y = (const int*)d_in[1];
  const float* We = (const float*)d_in[2];
  const float* Wp = (const float*)d_in[3];
  const float* bp = (const float*)d_in[4];
  const float* Wg = (const float*)d_in[5];
  const float* bg = (const float*)d_in[6];
  float* out = (float*)d_out;

  float* ws = (float*)d_ws;
  float* T = ws;              // 22*512 floats
  float* G = ws + 11264;      // 814 (22x37 padded)
  float* u = G + 814;         // 22
  float* v = u + 22;          // 22
  float* A = v + 22;          // 16
  float* Ftots = A + 16;      // 16
  float* Fws = (float*)((char*)d_ws + (1 << 20));  // 16 MiB: F, then E (diag-major)
  float* Gws = out;                                 // 16 MiB: suffix B (rev diag-major)

  k_T<<<22, 512, 0, stream>>>(We, Wp, bp, T);
  k_G<<<22, 512, 0, stream>>>(T, Wg, G, u, v);
  k_A<<<16, 256, 0, stream>>>(x, y, u, v, bg, A);
  k_nw<<<32, 512, 0, stream>>>(x, y, G, A, Fws, Gws, Ftots);
  k_E<<<128, 512, 0, stream>>>(Gws, Ftots, Fws);
  k_tr<<<16 * 64, 256, 0, stream>>>(Fws, out);
}

// Round 18
// 240.076 us; speedup vs baseline: 2.2962x; 1.2061x over previous
//
#include <hip/hip_runtime.h>
#include <stdint.h>

#define NEGF (-1.0e8f)
#define NCELL (512 * 512)
#define INVLN2 1.4426950408889634f
#define NIV 71  // intervals of 16 diagonals; skew 16/wave

// raw barrier: LDS ordering only (never drains vmcnt -> global ops stay in flight)
#define BAR() asm volatile("s_waitcnt lgkmcnt(0)\n\ts_barrier" ::: "memory")

#define REP16(X) X(0) X(1) X(2) X(3) X(4) X(5) X(6) X(7) X(8) X(9) X(10) X(11) X(12) X(13) X(14) X(15)

__device__ __forceinline__ float exp2f_(float x) {
#if __has_builtin(__builtin_amdgcn_exp2f)
  return __builtin_amdgcn_exp2f(x);
#else
  return exp2f(x);
#endif
}
__device__ __forceinline__ float log2f_(float x) {
#if __has_builtin(__builtin_amdgcn_logf)
  return __builtin_amdgcn_logf(x);
#else
  return log2f(x);
#endif
}

// DPP wave shift: 0x138 wave_shr:1 (lane l <- l-1, lane0 <- old)
__device__ __forceinline__ float dpp_shr1_f(float src, float old0) {
  return __int_as_float(__builtin_amdgcn_update_dpp(
      __float_as_int(old0), __float_as_int(src), 0x138, 0xF, 0xF, false));
}

// offset of diagonal d; lo(d)=max(1,d-512)
__device__ __forceinline__ int offd(int d) {
  return (d <= 513) ? (((d - 2) * (d - 1)) >> 1)
                    : (NCELL - (((1025 - d) * (1026 - d)) >> 1));
}
__device__ __forceinline__ int dbase(int d) {
  const int lo = (d > 513) ? d - 512 : 1;
  return offd(d) - lo;
}

// forward softmax-LSE cell (base-2 domain): nv = th + lsev
__device__ __forceinline__ void fcellF(float& nv, float& lsev, float dg, float up0,
                                       float lf0, float th, float A2) {
  float up = up0 + A2, lf = lf0 + A2;
  float mx = fmaxf(fmaxf(dg, up), lf);
  float s = exp2f_(dg - mx) + exp2f_(up - mx) + exp2f_(lf - mx);
  lsev = mx + log2f_(s);
  nv = th + lsev;
}

// ---------------------------------------------------------------------------
// K1: T[22][512] = W_embed @ W_proj + b_proj
// ---------------------------------------------------------------------------
__global__ void k_T(const float* __restrict__ We, const float* __restrict__ Wp,
                    const float* __restrict__ bp, float* __restrict__ T) {
  int a = blockIdx.x, c = threadIdx.x;
  __shared__ float e[512];
  e[c] = We[a * 512 + c];
  __syncthreads();
  float acc = bp[c];
#pragma unroll 8
  for (int k = 0; k < 512; ++k) acc = fmaf(e[k], Wp[k * 512 + c], acc);
  T[a * 512 + c] = acc;
}

// ---------------------------------------------------------------------------
// K2 (parallelized): block a computes G2[a][0..21] (stride 37), u[a], v[a].
// ---------------------------------------------------------------------------
__global__ __launch_bounds__(512) void k_G(const float* __restrict__ T, const float* __restrict__ Wg,
                                           float* __restrict__ G, float* __restrict__ u,
                                           float* __restrict__ v) {
  const int a = blockIdx.x;  // 22 blocks
  const int tid = threadIdx.x;
  const int wv = tid >> 6, lane = tid & 63;
  __shared__ float Ta[512];
  Ta[tid] = T[a * 512 + tid];
  __syncthreads();
  for (int j = wv; j < 24; j += 8) {
    const float* src = (j < 22) ? &T[j * 512] : &Wg[(j - 22) * 512];
    float s = 0.f;
#pragma unroll
    for (int c0 = 0; c0 < 512; c0 += 64) s = fmaf(Ta[c0 + lane], src[c0 + lane], s);
    for (int o = 32; o > 0; o >>= 1) s += __shfl_down(s, o, 64);
    if (lane == 0) {
      if (j < 22) G[a * 37 + j] = s * INVLN2;
      else if (j == 22) u[a] = s;
      else v[a] = s;
    }
  }
}

// ---------------------------------------------------------------------------
// K3: A2[b]
// ---------------------------------------------------------------------------
__global__ void k_A(const int* __restrict__ x, const int* __restrict__ y,
                    const float* __restrict__ u, const float* __restrict__ v,
                    const float* __restrict__ bg, float* __restrict__ A) {
  int b = blockIdx.x, t = threadIdx.x;
  const int* xb = x + b * 512;
  const int* yb = y + b * 512;
  float s = u[xb[t]] + u[xb[t + 256]] + v[yb[t]] + v[yb[t + 256]];
  for (int o = 32; o > 0; o >>= 1) s += __shfl_down(s, o, 64);
  __shared__ float w[4];
  if ((t & 63) == 0) w[t >> 6] = s;
  __syncthreads();
  if (t == 0) A[b] = ((w[0] + w[1] + w[2] + w[3]) * (1.0f / 512.0f) + bg[0]) * INVLN2;
}

// ---------------------------------------------------------------------------
// K4: forward-only skewed 8-wave pipeline DP with wave-local re-centering.
//     32 blocks: block 2b   -> F sweep of batch b (stores full F, diag-major)
//                block 2b+1 -> suffix sweep on REVERSED x,y (stores lse-part
//                              = B[513-i',513-j'], rev diag-major).
// ---------------------------------------------------------------------------
__global__ __launch_bounds__(512) void k_nw(const int* __restrict__ x, const int* __restrict__ y,
                                            const float* __restrict__ G,
                                            const float* __restrict__ Aarr,
                                            float* __restrict__ Fws,
                                            float* __restrict__ Gws,
                                            float* __restrict__ Ftots) {
  const int tid = threadIdx.x;
  const int wl = __builtin_amdgcn_readfirstlane(tid) >> 6;  // wave id, forced SGPR
  const int lane = tid & 63;
  __shared__ float Gl[814];       // 22 x 37
  __shared__ int ysPad[1856];     // zeros [0,640), ys [640,1152), zeros [1152,1856)
  __shared__ float Vring[8][256]; // slot(d)=(d-2)&127, copy at +128; ABSOLUTE values

  const int bb = blockIdx.x;
  const int b = bb >> 1;
  const bool rev = (bb & 1) != 0;
  const int* xbp = x + b * 512;
  const int* ybp = y + b * 512;
  for (int k = tid; k < 640; k += 512) ysPad[k] = 0;
  for (int k = 1152 + tid; k < 1856; k += 512) ysPad[k] = 0;
  ysPad[640 + tid] = ybp[rev ? 511 - tid : tid];
  for (int k = tid; k < 814; k += 512) Gl[k] = G[k];
  for (int k = tid; k < 2048; k += 512) ((float*)Vring)[k] = NEGF;
  const float A2 = Aarr[b];
  const int r = 64 * wl + lane + 1;
  const int xr = xbp[rev ? 512 - r : r - 1] * 37;
  const bool lane0 = (lane == 0), lane63 = (lane == 63);
  const bool wlt7 = (wl < 7);
  float* __restrict__ dst = (rev ? Gws : Fws) + (size_t)b * NCELL;
  __syncthreads();

  const int ivLoF = 5 * wl;
  const int ivHiF = (5 * wl + 35 < NIV - 1) ? 5 * wl + 35 : NIV - 1;
  const int dnP0 = 2 + 64 * wl;  // dn0 at ivLoF

#define DECLTH(m) float th##m;
  REP16(DECLTH)
#define DECLYA(m) int ya##m;
  REP16(DECLYA)
#define PROTH(m) { const int ix = (dnP0 + (m)) + 639 - r; th##m = Gl[xr + ysPad[ix]]; }
  REP16(PROTH)

  float va = NEGF, rupP = NEGF, Off = 0.0f;
#pragma unroll 1
  for (int iv = 0; iv < NIV; ++iv) {
    if (iv >= ivLoF && iv <= ivHiF) {
      // ---- re-center: subtract wave-uniform offset (lse shift-invariance) ----
      {
        float o = __int_as_float(__builtin_amdgcn_readfirstlane(__float_as_int(va)));
        o = (fabsf(o) < 1.0e7f) ? o : 0.0f;
        va -= o; rupP -= o; Off += o;
      }
      const int dn0 = 2 - 16 * wl + 16 * iv;  // scalar
      const int s0 = (dn0 - 2) & 127;        // multiple of 16
      const int A = (s0 == 0) ? 124 : s0 - 4;
      const float* VrB = &Vring[wl][A];
      float4 F0 = *(const float4*)&VrB[0];
      float4 F1 = *(const float4*)&VrB[4];
      float4 F2 = *(const float4*)&VrB[8];
      float4 F3 = *(const float4*)&VrB[12];
      float4 F4 = *(const float4*)&VrB[16];
      // ring holds ABSOLUTE values -> bring into local offset domain
#define SUBO(V) V.x -= Off; V.y -= Off; V.z -= Off; V.w -= Off;
      SUBO(F0) SUBO(F1) SUBO(F2) SUBO(F3) SUBO(F4)
      // batch-load next interval's ys into registers (stride-1)
      const int iya = dn0 + 655 - r;
#define LYA(m) ya##m = ysPad[iya + (m)];
      REP16(LYA)
#define DECLST(m) float st##m;
      REP16(DECLST)

#define FSTEP(m, RVC) { \
    const int dn = dn0 + (m); \
    float rdg = rupP; \
    if ((m) == 0 && wl == 0 && iv == 0) rdg = lane0 ? 0.0f : rdg; /* corner=0 */ \
    const float rup = dpp_shr1_f(va, (RVC)); \
    float nv, lsv; \
    fcellF(nv, lsv, rdg, rup, va, th##m, A2); \
    const bool vv = (unsigned)(dn - r - 1) < 512u; \
    if (vv) dst[dbase(dn) + r] = (rev ? lsv : nv) + Off; \
    if (!rev && dn == 1024 && r == 512) Ftots[b] = nv + Off; \
    nv = vv ? nv : NEGF; \
    st##m = nv; \
    th##m = Gl[xr + ya##m]; \
    va = nv; rupP = rup; \
  }
      FSTEP(0, F0.w)  FSTEP(1, F1.x)  FSTEP(2, F1.y)  FSTEP(3, F1.z)  FSTEP(4, F1.w)
      FSTEP(5, F2.x)  FSTEP(6, F2.y)  FSTEP(7, F2.z)  FSTEP(8, F2.w)
      FSTEP(9, F3.x)  FSTEP(10, F3.y) FSTEP(11, F3.z) FSTEP(12, F3.w)
      FSTEP(13, F4.x) FSTEP(14, F4.y) FSTEP(15, F4.z)

      if (wlt7 && lane63) {  // batched boundary publish (absolute): diags [dn0, dn0+15]
        const float4 S0 = make_float4(st0 + Off, st1 + Off, st2 + Off, st3 + Off);
        const float4 S1 = make_float4(st4 + Off, st5 + Off, st6 + Off, st7 + Off);
        const float4 S2 = make_float4(st8 + Off, st9 + Off, st10 + Off, st11 + Off);
        const float4 S3 = make_float4(st12 + Off, st13 + Off, st14 + Off, st15 + Off);
        float* Wp_ = &Vring[wl + 1][s0];
        *(float4*)&Wp_[0] = S0;
        *(float4*)&Wp_[4] = S1;
        *(float4*)&Wp_[8] = S2;
        *(float4*)&Wp_[12] = S3;
        *(float4*)&Wp_[128] = S0;
        *(float4*)&Wp_[132] = S1;
        *(float4*)&Wp_[136] = S2;
        *(float4*)&Wp_[140] = S3;
      }
    }
    BAR();
  }
}

// ---------------------------------------------------------------------------
// K4b (fallback): E = exp2(F + B - Ftot), in place over Fws (diag-major).
// ---------------------------------------------------------------------------
__global__ __launch_bounds__(512) void k_E(const float* __restrict__ Gws,
                                           const float* __restrict__ Ftots,
                                           float* __restrict__ Fws) {
  const int blk = blockIdx.x;
  const int b = blk >> 3, seg = blk & 7;
  const int tid = threadIdx.x;
  const float* Gs = Gws + (size_t)b * NCELL;
  float* Fs = Fws + (size_t)b * NCELL;
  const float Ftot = Ftots[b];
  for (int d = 2 + seg; d <= 1024; d += 8) {
    const int lo = (d > 513) ? d - 512 : 1;
    const int hi = (d - 1 < 512) ? d - 1 : 512;
    const int i = lo + tid;
    if (i <= hi) {
      const int dp = 1026 - d, ip = 513 - i;
      const int lop = (dp > 513) ? dp - 512 : 1;
      const int sf = offd(d) - lo + i;
      const float F = Fs[sf];
      const float Gv = Gs[offd(dp) - lop + ip];
      Fs[sf] = exp2f_(F + Gv - Ftot);
    }
  }
}

// ---------------------------------------------------------------------------
// K5 (fallback): transpose diag-major E (ws) -> row-major out.
// ---------------------------------------------------------------------------
__global__ __launch_bounds__(256) void k_tr(const float* __restrict__ ews, float* __restrict__ out) {
  const int blk = blockIdx.x;
  const int b = blk >> 6, ti = (blk >> 3) & 7, tj = blk & 7;
  const float* src = ews + (size_t)b * NCELL;
  float* dst = out + (size_t)b * NCELL;
  __shared__ float tile[64][68];
  const int i0 = ti * 64, j0 = tj * 64;
  const int t = threadIdx.x;
  const int sub = t >> 6, lane = t & 63;
  for (int k = sub; k < 127; k += 4) {
    const int d = i0 + j0 + 2 + k;
    const int ilo_t = max(i0 + 1, d - (j0 + 64));
    const int ihi_t = min(i0 + 64, d - (j0 + 1));
    const int i = ilo_t + lane;
    if (i <= ihi_t) {
      const int lo = (d > 513) ? d - 512 : 1;
      tile[i - 1 - i0][d - i - 1 - j0] = src[offd(d) - lo + i];
    }
  }
  __syncthreads();
  const int rr = t >> 2, q = (t & 3) * 16;
  float4* drow = (float4*)&dst[(size_t)(i0 + rr) * 512 + j0 + q];
  const float* srow = &tile[rr][q];
  drow[0] = *(const float4*)&srow[0];
  drow[1] = *(const float4*)&srow[4];
  drow[2] = *(const float4*)&srow[8];
  drow[3] = *(const float4*)&srow[12];
}

// ---------------------------------------------------------------------------
// K5f (fused): E = exp2(F + B - Ftot) computed inline during tile gather,
//              written row-major to out. Replaces k_E + k_tr when ws is large.
// ---------------------------------------------------------------------------
__global__ __launch_bounds__(256) void k_ET(const float* __restrict__ Fws,
                                            const float* __restrict__ Bws,
                                            const float* __restrict__ Ftots,
                                            float* __restrict__ out) {
  const int blk = blockIdx.x;
  const int b = blk >> 6, ti = (blk >> 3) & 7, tj = blk & 7;
  const float* Fs = Fws + (size_t)b * NCELL;
  const float* Bs = Bws + (size_t)b * NCELL;
  float* dst = out + (size_t)b * NCELL;
  const float Ftot = Ftots[b];
  __shared__ float tile[64][68];
  const int i0 = ti * 64, j0 = tj * 64;
  const int t = threadIdx.x;
  const int sub = t >> 6, lane = t & 63;
  for (int k = sub; k < 127; k += 4) {
    const int d = i0 + j0 + 2 + k;
    const int ilo_t = max(i0 + 1, d - (j0 + 64));
    const int ihi_t = min(i0 + 64, d - (j0 + 1));
    const int i = ilo_t + lane;
    if (i <= ihi_t) {
      const int lo = (d > 513) ? d - 512 : 1;
      const float F = Fs[offd(d) - lo + i];
      const int dp = 1026 - d, ip = 513 - i;
      const int lop = (dp > 513) ? dp - 512 : 1;
      const float B = Bs[offd(dp) - lop + ip];
      tile[i - 1 - i0][d - i - 1 - j0] = exp2f_(F + B - Ftot);
    }
  }
  __syncthreads();
  const int rr = t >> 2, q = (t & 3) * 16;
  float4* drow = (float4*)&dst[(size_t)(i0 + rr) * 512 + j0 + q];
  const float* srow = &tile[rr][q];
  drow[0] = *(const float4*)&srow[0];
  drow[1] = *(const float4*)&srow[4];
  drow[2] = *(const float4*)&srow[8];
  drow[3] = *(const float4*)&srow[12];
}

// ---------------------------------------------------------------------------
extern "C" void kernel_launch(void* const* d_in, const int* in_sizes, int n_in,
                              void* d_out, int out_size, void* d_ws, size_t ws_size,
                              hipStream_t stream) {
  const int* x = (const int*)d_in[0];
  const int* y = (const int*)d_in[1];
  const float* We = (const float*)d_in[2];
  const float* Wp = (const float*)d_in[3];
  const float* bp = (const float*)d_in[4];
  const float* Wg = (const float*)d_in[5];
  const float* bg = (const float*)d_in[6];
  float* out = (float*)d_out;

  float* ws = (float*)d_ws;
  float* T = ws;              // 22*512 floats
  float* G = ws + 11264;      // 814 (22x37 padded)
  float* u = G + 814;         // 22
  float* v = u + 22;          // 22
  float* A = v + 22;          // 16
  float* Ftots = A + 16;      // 16
  float* Fws = (float*)((char*)d_ws + (1 << 20));  // 16.78 MiB: F (diag-major)

  k_T<<<22, 512, 0, stream>>>(We, Wp, bp, T);
  k_G<<<22, 512, 0, stream>>>(T, Wg, G, u, v);
  k_A<<<16, 256, 0, stream>>>(x, y, u, v, bg, A);

  const bool fused = ws_size >= ((size_t)35 << 20);
  if (fused) {
    float* Bws = (float*)((char*)d_ws + ((size_t)18 << 20));  // 16.78 MiB: suffix B
    k_nw<<<32, 512, 0, stream>>>(x, y, G, A, Fws, Bws, Ftots);
    k_ET<<<16 * 64, 256, 0, stream>>>(Fws, Bws, Ftots, out);
  } else {
    float* Gws = out;  // suffix B parked in out (round-17 fallback path)
    k_nw<<<32, 512, 0, stream>>>(x, y, G, A, Fws, Gws, Ftots);
    k_E<<<128, 512, 0, stream>>>(Gws, Ftots, Fws);
    k_tr<<<16 * 64, 256, 0, stream>>>(Fws, out);
  }
}

// Round 19
// 237.360 us; speedup vs baseline: 2.3225x; 1.0114x over previous
//
#include <hip/hip_runtime.h>
#include <stdint.h>

#define NEGF (-1.0e8f)
#define NCELL (512 * 512)
#define INVLN2 1.4426950408889634f
#define NIV 71  // intervals of 16 diagonals; skew 16/wave

// raw barrier: LDS ordering only (never drains vmcnt -> global ops stay in flight)
#define BAR() asm volatile("s_waitcnt lgkmcnt(0)\n\ts_barrier" ::: "memory")

#define REP16(X) X(0) X(1) X(2) X(3) X(4) X(5) X(6) X(7) X(8) X(9) X(10) X(11) X(12) X(13) X(14) X(15)

__device__ __forceinline__ float exp2f_(float x) {
#if __has_builtin(__builtin_amdgcn_exp2f)
  return __builtin_amdgcn_exp2f(x);
#else
  return exp2f(x);
#endif
}
__device__ __forceinline__ float log2f_(float x) {
#if __has_builtin(__builtin_amdgcn_logf)
  return __builtin_amdgcn_logf(x);
#else
  return log2f(x);
#endif
}

// DPP wave shift: 0x138 wave_shr:1 (lane l <- l-1, lane0 <- old)
__device__ __forceinline__ float dpp_shr1_f(float src, float old0) {
  return __int_as_float(__builtin_amdgcn_update_dpp(
      __float_as_int(old0), __float_as_int(src), 0x138, 0xF, 0xF, false));
}

// offset of diagonal d; lo(d)=max(1,d-512)
__device__ __forceinline__ int offd(int d) {
  return (d <= 513) ? (((d - 2) * (d - 1)) >> 1)
                    : (NCELL - (((1025 - d) * (1026 - d)) >> 1));
}
__device__ __forceinline__ int dbase(int d) {
  const int lo = (d > 513) ? d - 512 : 1;
  return offd(d) - lo;
}

// forward softmax-LSE cell (base-2 domain): nv = th + lsev
__device__ __forceinline__ void fcellF(float& nv, float& lsev, float dg, float up0,
                                       float lf0, float th, float A2) {
  float up = up0 + A2, lf = lf0 + A2;
  float mx = fmaxf(fmaxf(dg, up), lf);
  float s = exp2f_(dg - mx) + exp2f_(up - mx) + exp2f_(lf - mx);
  lsev = mx + log2f_(s);
  nv = th + lsev;
}

// ---------------------------------------------------------------------------
// K1: T[22][512] = W_embed @ W_proj + b_proj
// ---------------------------------------------------------------------------
__global__ void k_T(const float* __restrict__ We, const float* __restrict__ Wp,
                    const float* __restrict__ bp, float* __restrict__ T) {
  int a = blockIdx.x, c = threadIdx.x;
  __shared__ float e[512];
  e[c] = We[a * 512 + c];
  __syncthreads();
  float acc = bp[c];
#pragma unroll 8
  for (int k = 0; k < 512; ++k) acc = fmaf(e[k], Wp[k * 512 + c], acc);
  T[a * 512 + c] = acc;
}

// ---------------------------------------------------------------------------
// K2 (parallelized): block a computes G2[a][0..21] (stride 37), u[a], v[a].
// ---------------------------------------------------------------------------
__global__ __launch_bounds__(512) void k_G(const float* __restrict__ T, const float* __restrict__ Wg,
                                           float* __restrict__ G, float* __restrict__ u,
                                           float* __restrict__ v) {
  const int a = blockIdx.x;  // 22 blocks
  const int tid = threadIdx.x;
  const int wv = tid >> 6, lane = tid & 63;
  __shared__ float Ta[512];
  Ta[tid] = T[a * 512 + tid];
  __syncthreads();
  for (int j = wv; j < 24; j += 8) {
    const float* src = (j < 22) ? &T[j * 512] : &Wg[(j - 22) * 512];
    float s = 0.f;
#pragma unroll
    for (int c0 = 0; c0 < 512; c0 += 64) s = fmaf(Ta[c0 + lane], src[c0 + lane], s);
    for (int o = 32; o > 0; o >>= 1) s += __shfl_down(s, o, 64);
    if (lane == 0) {
      if (j < 22) G[a * 37 + j] = s * INVLN2;
      else if (j == 22) u[a] = s;
      else v[a] = s;
    }
  }
}

// ---------------------------------------------------------------------------
// K4: forward-only skewed 8-wave pipeline DP with wave-local re-centering.
//     32 blocks: block 2b   -> F sweep of batch b (stores full F, diag-major)
//                block 2b+1 -> suffix sweep on REVERSED x,y (stores lse-part
//                              = B[513-i',513-j'], rev diag-major).
//     A2[b] computed in-block (k_A folded into prologue).
// ---------------------------------------------------------------------------
__global__ __launch_bounds__(512) void k_nw(const int* __restrict__ x, const int* __restrict__ y,
                                            const float* __restrict__ G,
                                            const float* __restrict__ u,
                                            const float* __restrict__ v,
                                            const float* __restrict__ bg,
                                            float* __restrict__ Fws,
                                            float* __restrict__ Gws,
                                            float* __restrict__ Ftots) {
  const int tid = threadIdx.x;
  const int wl = __builtin_amdgcn_readfirstlane(tid) >> 6;  // wave id, forced SGPR
  const int lane = tid & 63;
  __shared__ float Gl[814];       // 22 x 37
  __shared__ int ysPad[1856];     // zeros [0,640), ys [640,1152), zeros [1152,1856)
  __shared__ float Vring[8][256]; // slot(d)=(d-2)&127, copy at +128; ABSOLUTE values
  __shared__ float red[8];

  const int bb = blockIdx.x;
  const int b = bb >> 1;
  const bool rev = (bb & 1) != 0;
  const int* xbp = x + b * 512;
  const int* ybp = y + b * 512;
  for (int k = tid; k < 640; k += 512) ysPad[k] = 0;
  for (int k = 1152 + tid; k < 1856; k += 512) ysPad[k] = 0;
  ysPad[640 + tid] = ybp[rev ? 511 - tid : tid];
  for (int k = tid; k < 814; k += 512) Gl[k] = G[k];
  for (int k = tid; k < 2048; k += 512) ((float*)Vring)[k] = NEGF;
  // ---- A2 (folded k_A): per-block redundant reduce ----
  {
    float sA = u[xbp[tid]] + v[ybp[tid]];
    for (int o = 32; o > 0; o >>= 1) sA += __shfl_down(sA, o, 64);
    if (lane == 0) red[wl] = sA;
  }
  const int r = 64 * wl + lane + 1;
  const int xr = xbp[rev ? 512 - r : r - 1] * 37;
  const bool lane0 = (lane == 0), lane63 = (lane == 63);
  const bool wlt7 = (wl < 7);
  float* __restrict__ dst = (rev ? Gws : Fws) + (size_t)b * NCELL;
  __syncthreads();
  const float A2 = ((red[0] + red[1] + red[2] + red[3] + red[4] + red[5] + red[6] + red[7]) *
                        (1.0f / 512.0f) + bg[0]) * INVLN2;

  const int ivLoF = 5 * wl;
  const int ivHiF = (5 * wl + 35 < NIV - 1) ? 5 * wl + 35 : NIV - 1;
  const int dnP0 = 2 + 64 * wl;  // dn0 at ivLoF

#define DECLTH(m) float th##m;
  REP16(DECLTH)
#define DECLYA(m) int ya##m;
  REP16(DECLYA)
#define PROTH(m) { const int ix = (dnP0 + (m)) + 639 - r; th##m = Gl[xr + ysPad[ix]]; }
  REP16(PROTH)

  float va = NEGF, rupP = NEGF, Off = 0.0f;
#pragma unroll 1
  for (int iv = 0; iv < NIV; ++iv) {
    if (iv >= ivLoF && iv <= ivHiF) {
      // ---- re-center: subtract wave-uniform offset (lse shift-invariance) ----
      {
        float o = __int_as_float(__builtin_amdgcn_readfirstlane(__float_as_int(va)));
        o = (fabsf(o) < 1.0e7f) ? o : 0.0f;
        va -= o; rupP -= o; Off += o;
      }
      const int dn0 = 2 - 16 * wl + 16 * iv;  // scalar
      const int s0 = (dn0 - 2) & 127;        // multiple of 16
      const int A = (s0 == 0) ? 124 : s0 - 4;
      const float* VrB = &Vring[wl][A];
      float4 F0 = *(const float4*)&VrB[0];
      float4 F1 = *(const float4*)&VrB[4];
      float4 F2 = *(const float4*)&VrB[8];
      float4 F3 = *(const float4*)&VrB[12];
      float4 F4 = *(const float4*)&VrB[16];
      // ring holds ABSOLUTE values -> bring into local offset domain
#define SUBO(V) V.x -= Off; V.y -= Off; V.z -= Off; V.w -= Off;
      SUBO(F0) SUBO(F1) SUBO(F2) SUBO(F3) SUBO(F4)
      // batch-load next interval's ys into registers (stride-1)
      const int iya = dn0 + 655 - r;
#define LYA(m) ya##m = ysPad[iya + (m)];
      REP16(LYA)
#define DECLST(m) float st##m;
      REP16(DECLST)

#define FSTEP(m, RVC) { \
    const int dn = dn0 + (m); \
    float rdg = rupP; \
    if ((m) == 0 && wl == 0 && iv == 0) rdg = lane0 ? 0.0f : rdg; /* corner=0 */ \
    const float rup = dpp_shr1_f(va, (RVC)); \
    float nv, lsv; \
    fcellF(nv, lsv, rdg, rup, va, th##m, A2); \
    const bool vv = (unsigned)(dn - r - 1) < 512u; \
    if (vv) dst[dbase(dn) + r] = (rev ? lsv : nv) + Off; \
    if (!rev && dn == 1024 && r == 512) Ftots[b] = nv + Off; \
    nv = vv ? nv : NEGF; \
    st##m = nv; \
    th##m = Gl[xr + ya##m]; \
    va = nv; rupP = rup; \
  }
      FSTEP(0, F0.w)  FSTEP(1, F1.x)  FSTEP(2, F1.y)  FSTEP(3, F1.z)  FSTEP(4, F1.w)
      FSTEP(5, F2.x)  FSTEP(6, F2.y)  FSTEP(7, F2.z)  FSTEP(8, F2.w)
      FSTEP(9, F3.x)  FSTEP(10, F3.y) FSTEP(11, F3.z) FSTEP(12, F3.w)
      FSTEP(13, F4.x) FSTEP(14, F4.y) FSTEP(15, F4.z)

      if (wlt7 && lane63) {  // batched boundary publish (absolute): diags [dn0, dn0+15]
        const float4 S0 = make_float4(st0 + Off, st1 + Off, st2 + Off, st3 + Off);
        const float4 S1 = make_float4(st4 + Off, st5 + Off, st6 + Off, st7 + Off);
        const float4 S2 = make_float4(st8 + Off, st9 + Off, st10 + Off, st11 + Off);
        const float4 S3 = make_float4(st12 + Off, st13 + Off, st14 + Off, st15 + Off);
        float* Wp_ = &Vring[wl + 1][s0];
        *(float4*)&Wp_[0] = S0;
        *(float4*)&Wp_[4] = S1;
        *(float4*)&Wp_[8] = S2;
        *(float4*)&Wp_[12] = S3;
        *(float4*)&Wp_[128] = S0;
        *(float4*)&Wp_[132] = S1;
        *(float4*)&Wp_[136] = S2;
        *(float4*)&Wp_[140] = S3;
      }
    }
    BAR();
  }
}

// ---------------------------------------------------------------------------
// K4b (fallback): E = exp2(F + B - Ftot), in place over Fws (diag-major).
// ---------------------------------------------------------------------------
__global__ __launch_bounds__(512) void k_E(const float* __restrict__ Gws,
                                           const float* __restrict__ Ftots,
                                           float* __restrict__ Fws) {
  const int blk = blockIdx.x;
  const int b = blk >> 3, seg = blk & 7;
  const int tid = threadIdx.x;
  const float* Gs = Gws + (size_t)b * NCELL;
  float* Fs = Fws + (size_t)b * NCELL;
  const float Ftot = Ftots[b];
  for (int d = 2 + seg; d <= 1024; d += 8) {
    const int lo = (d > 513) ? d - 512 : 1;
    const int hi = (d - 1 < 512) ? d - 1 : 512;
    const int i = lo + tid;
    if (i <= hi) {
      const int dp = 1026 - d, ip = 513 - i;
      const int lop = (dp > 513) ? dp - 512 : 1;
      const int sf = offd(d) - lo + i;
      const float F = Fs[sf];
      const float Gv = Gs[offd(dp) - lop + ip];
      Fs[sf] = exp2f_(F + Gv - Ftot);
    }
  }
}

// ---------------------------------------------------------------------------
// K5 (fallback): transpose diag-major E (ws) -> row-major out.
// ---------------------------------------------------------------------------
__global__ __launch_bounds__(256) void k_tr(const float* __restrict__ ews, float* __restrict__ out) {
  const int blk = blockIdx.x;
  const int b = blk >> 6, ti = (blk >> 3) & 7, tj = blk & 7;
  const float* src = ews + (size_t)b * NCELL;
  float* dst = out + (size_t)b * NCELL;
  __shared__ float tile[64][68];
  const int i0 = ti * 64, j0 = tj * 64;
  const int t = threadIdx.x;
  const int sub = t >> 6, lane = t & 63;
  for (int k = sub; k < 127; k += 4) {
    const int d = i0 + j0 + 2 + k;
    const int ilo_t = max(i0 + 1, d - (j0 + 64));
    const int ihi_t = min(i0 + 64, d - (j0 + 1));
    const int i = ilo_t + lane;
    if (i <= ihi_t) {
      const int lo = (d > 513) ? d - 512 : 1;
      tile[i - 1 - i0][d - i - 1 - j0] = src[offd(d) - lo + i];
    }
  }
  __syncthreads();
  const int rr = t >> 2, q = (t & 3) * 16;
  float4* drow = (float4*)&dst[(size_t)(i0 + rr) * 512 + j0 + q];
  const float* srow = &tile[rr][q];
  drow[0] = *(const float4*)&srow[0];
  drow[1] = *(const float4*)&srow[4];
  drow[2] = *(const float4*)&srow[8];
  drow[3] = *(const float4*)&srow[12];
}

// ---------------------------------------------------------------------------
// K5f (fused): E = exp2(F + B - Ftot) computed inline during tile gather,
//              written row-major to out. Replaces k_E + k_tr when ws is large.
// ---------------------------------------------------------------------------
__global__ __launch_bounds__(256) void k_ET(const float* __restrict__ Fws,
                                            const float* __restrict__ Bws,
                                            const float* __restrict__ Ftots,
                                            float* __restrict__ out) {
  const int blk = blockIdx.x;
  const int b = blk >> 6, ti = (blk >> 3) & 7, tj = blk & 7;
  const float* Fs = Fws + (size_t)b * NCELL;
  const float* Bs = Bws + (size_t)b * NCELL;
  float* dst = out + (size_t)b * NCELL;
  const float Ftot = Ftots[b];
  __shared__ float tile[64][68];
  const int i0 = ti * 64, j0 = tj * 64;
  const int t = threadIdx.x;
  const int sub = t >> 6, lane = t & 63;
  for (int k = sub; k < 127; k += 4) {
    const int d = i0 + j0 + 2 + k;
    const int ilo_t = max(i0 + 1, d - (j0 + 64));
    const int ihi_t = min(i0 + 64, d - (j0 + 1));
    const int i = ilo_t + lane;
    if (i <= ihi_t) {
      const int lo = (d > 513) ? d - 512 : 1;
      const float F = Fs[offd(d) - lo + i];
      const int dp = 1026 - d, ip = 513 - i;
      const int lop = (dp > 513) ? dp - 512 : 1;
      const float B = Bs[offd(dp) - lop + ip];
      tile[i - 1 - i0][d - i - 1 - j0] = exp2f_(F + B - Ftot);
    }
  }
  __syncthreads();
  const int rr = t >> 2, q = (t & 3) * 16;
  float4* drow = (float4*)&dst[(size_t)(i0 + rr) * 512 + j0 + q];
  const float* srow = &tile[rr][q];
  drow[0] = *(const float4*)&srow[0];
  drow[1] = *(const float4*)&srow[4];
  drow[2] = *(const float4*)&srow[8];
  drow[3] = *(const float4*)&srow[12];
}

// ---------------------------------------------------------------------------
extern "C" void kernel_launch(void* const* d_in, const int* in_sizes, int n_in,
                              void* d_out, int out_size, void* d_ws, size_t ws_size,
                              hipStream_t stream) {
  const int* x = (const int*)d_in[0];
  const int* y = (const int*)d_in[1];
  const float* We = (const float*)d_in[2];
  const float* Wp = (const float*)d_in[3];
  const float* bp = (const float*)d_in[4];
  const float* Wg = (const float*)d_in[5];
  const float* bg = (const float*)d_in[6];
  float* out = (float*)d_out;

  float* ws = (float*)d_ws;
  float* T = ws;              // 22*512 floats
  float* G = ws + 11264;      // 814 (22x37 padded)
  float* u = G + 814;         // 22
  float* v = u + 22;          // 22
  float* Ftots = v + 22;      // 16
  float* Fws = (float*)((char*)d_ws + (1 << 20));  // 16.78 MiB: F (diag-major)

  k_T<<<22, 512, 0, stream>>>(We, Wp, bp, T);
  k_G<<<22, 512, 0, stream>>>(T, Wg, G, u, v);

  const bool fused = ws_size >= ((size_t)35 << 20);
  if (fused) {
    float* Bws = (float*)((char*)d_ws + ((size_t)18 << 20));  // 16.78 MiB: suffix B
    k_nw<<<32, 512, 0, stream>>>(x, y, G, u, v, bg, Fws, Bws, Ftots);
    k_ET<<<16 * 64, 256, 0, stream>>>(Fws, Bws, Ftots, out);
  } else {
    float* Gws = out;  // suffix B parked in out (fallback path)
    k_nw<<<32, 512, 0, stream>>>(x, y, G, u, v, bg, Fws, Gws, Ftots);
    k_E<<<128, 512, 0, stream>>>(Gws, Ftots, Fws);
    k_tr<<<16 * 64, 256, 0, stream>>>(Fws, out);
  }
}

// Round 20
// 237.174 us; speedup vs baseline: 2.3243x; 1.0008x over previous
//
#include <hip/hip_runtime.h>
#include <stdint.h>

#define NEGF (-1.0e8f)
#define NCELL (512 * 512)
#define INVLN2 1.4426950408889634f
#define NIV 71  // intervals of 16 diagonals; skew 16/wave

// raw barrier: LDS ordering only (never drains vmcnt -> global ops stay in flight)
#define BAR() asm volatile("s_waitcnt lgkmcnt(0)\n\ts_barrier" ::: "memory")

#define REP16(X) X(0) X(1) X(2) X(3) X(4) X(5) X(6) X(7) X(8) X(9) X(10) X(11) X(12) X(13) X(14) X(15)

__device__ __forceinline__ float exp2f_(float x) {
#if __has_builtin(__builtin_amdgcn_exp2f)
  return __builtin_amdgcn_exp2f(x);
#else
  return exp2f(x);
#endif
}
__device__ __forceinline__ float log2f_(float x) {
#if __has_builtin(__builtin_amdgcn_logf)
  return __builtin_amdgcn_logf(x);
#else
  return log2f(x);
#endif
}

// DPP wave shift: 0x138 wave_shr:1 (lane l <- l-1, lane0 <- old)
__device__ __forceinline__ float dpp_shr1_f(float src, float old0) {
  return __int_as_float(__builtin_amdgcn_update_dpp(
      __float_as_int(old0), __float_as_int(src), 0x138, 0xF, 0xF, false));
}

// offset of diagonal d; lo(d)=max(1,d-512)
__device__ __forceinline__ int offd(int d) {
  return (d <= 513) ? (((d - 2) * (d - 1)) >> 1)
                    : (NCELL - (((1025 - d) * (1026 - d)) >> 1));
}
__device__ __forceinline__ int dbase(int d) {
  const int lo = (d > 513) ? d - 512 : 1;
  return offd(d) - lo;
}

// forward softmax-LSE cell (base-2 domain): nv = th + lsev
__device__ __forceinline__ void fcellF(float& nv, float& lsev, float dg, float up0,
                                       float lf0, float th, float A2) {
  float up = up0 + A2, lf = lf0 + A2;
  float mx = fmaxf(fmaxf(dg, up), lf);
  float s = exp2f_(dg - mx) + exp2f_(up - mx) + exp2f_(lf - mx);
  lsev = mx + log2f_(s);
  nv = th + lsev;
}

// ---------------------------------------------------------------------------
// K1: T[22][512] = W_embed @ W_proj + b_proj
// ---------------------------------------------------------------------------
__global__ void k_T(const float* __restrict__ We, const float* __restrict__ Wp,
                    const float* __restrict__ bp, float* __restrict__ T) {
  int a = blockIdx.x, c = threadIdx.x;
  __shared__ float e[512];
  e[c] = We[a * 512 + c];
  __syncthreads();
  float acc = bp[c];
#pragma unroll 8
  for (int k = 0; k < 512; ++k) acc = fmaf(e[k], Wp[k * 512 + c], acc);
  T[a * 512 + c] = acc;
}

// ---------------------------------------------------------------------------
// K2 (parallelized): block a computes G2[a][0..21] (stride 37), u[a], v[a].
// ---------------------------------------------------------------------------
__global__ __launch_bounds__(512) void k_G(const float* __restrict__ T, const float* __restrict__ Wg,
                                           float* __restrict__ G, float* __restrict__ u,
                                           float* __restrict__ v) {
  const int a = blockIdx.x;  // 22 blocks
  const int tid = threadIdx.x;
  const int wv = tid >> 6, lane = tid & 63;
  __shared__ float Ta[512];
  Ta[tid] = T[a * 512 + tid];
  __syncthreads();
  for (int j = wv; j < 24; j += 8) {
    const float* src = (j < 22) ? &T[j * 512] : &Wg[(j - 22) * 512];
    float s = 0.f;
#pragma unroll
    for (int c0 = 0; c0 < 512; c0 += 64) s = fmaf(Ta[c0 + lane], src[c0 + lane], s);
    for (int o = 32; o > 0; o >>= 1) s += __shfl_down(s, o, 64);
    if (lane == 0) {
      if (j < 22) G[a * 37 + j] = s * INVLN2;
      else if (j == 22) u[a] = s;
      else v[a] = s;
    }
  }
}

// ---------------------------------------------------------------------------
// K4: forward-only skewed 8-wave pipeline DP with wave-local re-centering.
//     32 blocks: block 2b   -> F sweep of batch b (stores full F, diag-major)
//                block 2b+1 -> suffix sweep on REVERSED x,y (stores lse-part
//                              = B[513-i',513-j'], rev diag-major).
//     A2[b] computed in-block. ys prefetch via 4-way shift-replicated table
//     (aligned ds_read_b128: 4 LDS ops instead of 16 per wave per interval).
// ---------------------------------------------------------------------------
__global__ __launch_bounds__(512) void k_nw(const int* __restrict__ x, const int* __restrict__ y,
                                            const float* __restrict__ G,
                                            const float* __restrict__ u,
                                            const float* __restrict__ v,
                                            const float* __restrict__ bg,
                                            float* __restrict__ Fws,
                                            float* __restrict__ Gws,
                                            float* __restrict__ Ftots) {
  const int tid = threadIdx.x;
  const int wl = __builtin_amdgcn_readfirstlane(tid) >> 6;  // wave id, forced SGPR
  const int lane = tid & 63;
  __shared__ float Gl[814];       // 22 x 37
  __shared__ int ysPad[1856];     // zeros [0,640), ys [640,1152), zeros [1152,1856)
  __shared__ int ysRep[4][1860];  // ysRep[s][q] = ysPadVal(q+s); rows 16B-aligned
  __shared__ float Vring[8][256]; // slot(d)=(d-2)&127, copy at +128; ABSOLUTE values
  __shared__ float red[8];

  const int bb = blockIdx.x;
  const int b = bb >> 1;
  const bool rev = (bb & 1) != 0;
  const int* xbp = x + b * 512;
  const int* ybp = y + b * 512;
  for (int k = tid; k < 640; k += 512) ysPad[k] = 0;
  for (int k = 1152 + tid; k < 1856; k += 512) ysPad[k] = 0;
  ysPad[640 + tid] = ybp[rev ? 511 - tid : tid];
  for (int k = tid; k < 814; k += 512) Gl[k] = G[k];
  for (int k = tid; k < 2048; k += 512) ((float*)Vring)[k] = NEGF;
  // ---- A2 (folded k_A): per-block redundant reduce ----
  {
    float sA = u[xbp[tid]] + v[ybp[tid]];
    for (int o = 32; o > 0; o >>= 1) sA += __shfl_down(sA, o, 64);
    if (lane == 0) red[wl] = sA;
  }
  __syncthreads();
  // build shift replicas (ysPad complete at this point)
  for (int k = tid; k < 4 * 1860; k += 512) {
    const int s = k / 1860, q = k - s * 1860;
    const int ix = q + s;
    ysRep[s][q] = (ix < 1856) ? ysPad[ix] : 0;
  }
  const int r = 64 * wl + lane + 1;
  const int xr = xbp[rev ? 512 - r : r - 1] * 37;
  const bool lane0 = (lane == 0), lane63 = (lane == 63);
  const bool wlt7 = (wl < 7);
  float* __restrict__ dst = (rev ? Gws : Fws) + (size_t)b * NCELL;
  __syncthreads();
  const float A2 = ((red[0] + red[1] + red[2] + red[3] + red[4] + red[5] + red[6] + red[7]) *
                        (1.0f / 512.0f) + bg[0]) * INVLN2;

  const int ivLoF = 5 * wl;
  const int ivHiF = (5 * wl + 35 < NIV - 1) ? 5 * wl + 35 : NIV - 1;
  const int dnP0 = 2 + 64 * wl;  // dn0 at ivLoF

#define DECLTH(m) float th##m;
  REP16(DECLTH)
#define PROTH(m) { const int ix = (dnP0 + (m)) + 639 - r; th##m = Gl[xr + ysPad[ix]]; }
  REP16(PROTH)

  float va = NEGF, rupP = NEGF, Off = 0.0f;
#pragma unroll 1
  for (int iv = 0; iv < NIV; ++iv) {
    if (iv >= ivLoF && iv <= ivHiF) {
      // ---- re-center: subtract wave-uniform offset (lse shift-invariance) ----
      {
        float o = __int_as_float(__builtin_amdgcn_readfirstlane(__float_as_int(va)));
        o = (fabsf(o) < 1.0e7f) ? o : 0.0f;
        va -= o; rupP -= o; Off += o;
      }
      const int dn0 = 2 - 16 * wl + 16 * iv;  // scalar
      const int s0 = (dn0 - 2) & 127;        // multiple of 16
      const int A = (s0 == 0) ? 124 : s0 - 4;
      const float* VrB = &Vring[wl][A];
      float4 F0 = *(const float4*)&VrB[0];
      float4 F1 = *(const float4*)&VrB[4];
      float4 F2 = *(const float4*)&VrB[8];
      float4 F3 = *(const float4*)&VrB[12];
      float4 F4 = *(const float4*)&VrB[16];
      // ring holds ABSOLUTE values -> bring into local offset domain
#define SUBO(V) V.x -= Off; V.y -= Off; V.z -= Off; V.w -= Off;
      SUBO(F0) SUBO(F1) SUBO(F2) SUBO(F3) SUBO(F4)
      // batch-load next interval's ys via aligned b128 from shift replica
      const int iya = dn0 + 655 - r;
      const int sr = iya & 3;
      const int q0 = iya - sr;  // 4-aligned within replica sr
      const int* Rp = &ysRep[sr][q0];
      const int4 Y0 = *(const int4*)&Rp[0];
      const int4 Y1 = *(const int4*)&Rp[4];
      const int4 Y2 = *(const int4*)&Rp[8];
      const int4 Y3 = *(const int4*)&Rp[12];
#define DECLST(m) float st##m;
      REP16(DECLST)

#define FSTEP(m, RVC, YAC) { \
    const int dn = dn0 + (m); \
    float rdg = rupP; \
    if ((m) == 0 && wl == 0 && iv == 0) rdg = lane0 ? 0.0f : rdg; /* corner=0 */ \
    const float rup = dpp_shr1_f(va, (RVC)); \
    float nv, lsv; \
    fcellF(nv, lsv, rdg, rup, va, th##m, A2); \
    const bool vv = (unsigned)(dn - r - 1) < 512u; \
    if (vv) dst[dbase(dn) + r] = (rev ? lsv : nv) + Off; \
    if (!rev && dn == 1024 && r == 512) Ftots[b] = nv + Off; \
    nv = vv ? nv : NEGF; \
    st##m = nv; \
    th##m = Gl[xr + (YAC)]; \
    va = nv; rupP = rup; \
  }
      FSTEP(0, F0.w, Y0.x)  FSTEP(1, F1.x, Y0.y)  FSTEP(2, F1.y, Y0.z)  FSTEP(3, F1.z, Y0.w)
      FSTEP(4, F1.w, Y1.x)  FSTEP(5, F2.x, Y1.y)  FSTEP(6, F2.y, Y1.z)  FSTEP(7, F2.z, Y1.w)
      FSTEP(8, F2.w, Y2.x)  FSTEP(9, F3.x, Y2.y)  FSTEP(10, F3.y, Y2.z) FSTEP(11, F3.z, Y2.w)
      FSTEP(12, F3.w, Y3.x) FSTEP(13, F4.x, Y3.y) FSTEP(14, F4.y, Y3.z) FSTEP(15, F4.z, Y3.w)

      if (wlt7 && lane63) {  // batched boundary publish (absolute): diags [dn0, dn0+15]
        const float4 S0 = make_float4(st0 + Off, st1 + Off, st2 + Off, st3 + Off);
        const float4 S1 = make_float4(st4 + Off, st5 + Off, st6 + Off, st7 + Off);
        const float4 S2 = make_float4(st8 + Off, st9 + Off, st10 + Off, st11 + Off);
        const float4 S3 = make_float4(st12 + Off, st13 + Off, st14 + Off, st15 + Off);
        float* Wp_ = &Vring[wl + 1][s0];
        *(float4*)&Wp_[0] = S0;
        *(float4*)&Wp_[4] = S1;
        *(float4*)&Wp_[8] = S2;
        *(float4*)&Wp_[12] = S3;
        *(float4*)&Wp_[128] = S0;
        *(float4*)&Wp_[132] = S1;
        *(float4*)&Wp_[136] = S2;
        *(float4*)&Wp_[140] = S3;
      }
    }
    BAR();
  }
}

// ---------------------------------------------------------------------------
// K4b (fallback): E = exp2(F + B - Ftot), in place over Fws (diag-major).
// ---------------------------------------------------------------------------
__global__ __launch_bounds__(512) void k_E(const float* __restrict__ Gws,
                                           const float* __restrict__ Ftots,
                                           float* __restrict__ Fws) {
  const int blk = blockIdx.x;
  const int b = blk >> 3, seg = blk & 7;
  const int tid = threadIdx.x;
  const float* Gs = Gws + (size_t)b * NCELL;
  float* Fs = Fws + (size_t)b * NCELL;
  const float Ftot = Ftots[b];
  for (int d = 2 + seg; d <= 1024; d += 8) {
    const int lo = (d > 513) ? d - 512 : 1;
    const int hi = (d - 1 < 512) ? d - 1 : 512;
    const int i = lo + tid;
    if (i <= hi) {
      const int dp = 1026 - d, ip = 513 - i;
      const int lop = (dp > 513) ? dp - 512 : 1;
      const int sf = offd(d) - lo + i;
      const float F = Fs[sf];
      const float Gv = Gs[offd(dp) - lop + ip];
      Fs[sf] = exp2f_(F + Gv - Ftot);
    }
  }
}

// ---------------------------------------------------------------------------
// K5 (fallback): transpose diag-major E (ws) -> row-major out.
// ---------------------------------------------------------------------------
__global__ __launch_bounds__(256) void k_tr(const float* __restrict__ ews, float* __restrict__ out) {
  const int blk = blockIdx.x;
  const int b = blk >> 6, ti = (blk >> 3) & 7, tj = blk & 7;
  const float* src = ews + (size_t)b * NCELL;
  float* dst = out + (size_t)b * NCELL;
  __shared__ float tile[64][68];
  const int i0 = ti * 64, j0 = tj * 64;
  const int t = threadIdx.x;
  const int sub = t >> 6, lane = t & 63;
  for (int k = sub; k < 127; k += 4) {
    const int d = i0 + j0 + 2 + k;
    const int ilo_t = max(i0 + 1, d - (j0 + 64));
    const int ihi_t = min(i0 + 64, d - (j0 + 1));
    const int i = ilo_t + lane;
    if (i <= ihi_t) {
      const int lo = (d > 513) ? d - 512 : 1;
      tile[i - 1 - i0][d - i - 1 - j0] = src[offd(d) - lo + i];
    }
  }
  __syncthreads();
  const int rr = t >> 2, q = (t & 3) * 16;
  float4* drow = (float4*)&dst[(size_t)(i0 + rr) * 512 + j0 + q];
  const float* srow = &tile[rr][q];
  drow[0] = *(const float4*)&srow[0];
  drow[1] = *(const float4*)&srow[4];
  drow[2] = *(const float4*)&srow[8];
  drow[3] = *(const float4*)&srow[12];
}

// ---------------------------------------------------------------------------
// K5f (fused): E = exp2(F + B - Ftot) computed inline during tile gather,
//              written row-major to out. Replaces k_E + k_tr when ws is large.
// ---------------------------------------------------------------------------
__global__ __launch_bounds__(256) void k_ET(const float* __restrict__ Fws,
                                            const float* __restrict__ Bws,
                                            const float* __restrict__ Ftots,
                                            float* __restrict__ out) {
  const int blk = blockIdx.x;
  const int b = blk >> 6, ti = (blk >> 3) & 7, tj = blk & 7;
  const float* Fs = Fws + (size_t)b * NCELL;
  const float* Bs = Bws + (size_t)b * NCELL;
  float* dst = out + (size_t)b * NCELL;
  const float Ftot = Ftots[b];
  __shared__ float tile[64][68];
  const int i0 = ti * 64, j0 = tj * 64;
  const int t = threadIdx.x;
  const int sub = t >> 6, lane = t & 63;
  for (int k = sub; k < 127; k += 4) {
    const int d = i0 + j0 + 2 + k;
    const int ilo_t = max(i0 + 1, d - (j0 + 64));
    const int ihi_t = min(i0 + 64, d - (j0 + 1));
    const int i = ilo_t + lane;
    if (i <= ihi_t) {
      const int lo = (d > 513) ? d - 512 : 1;
      const float F = Fs[offd(d) - lo + i];
      const int dp = 1026 - d, ip = 513 - i;
      const int lop = (dp > 513) ? dp - 512 : 1;
      const float B = Bs[offd(dp) - lop + ip];
      tile[i - 1 - i0][d - i - 1 - j0] = exp2f_(F + B - Ftot);
    }
  }
  __syncthreads();
  const int rr = t >> 2, q = (t & 3) * 16;
  float4* drow = (float4*)&dst[(size_t)(i0 + rr) * 512 + j0 + q];
  const float* srow = &tile[rr][q];
  drow[0] = *(const float4*)&srow[0];
  drow[1] = *(const float4*)&srow[4];
  drow[2] = *(const float4*)&srow[8];
  drow[3] = *(const float4*)&srow[12];
}

// ---------------------------------------------------------------------------
extern "C" void kernel_launch(void* const* d_in, const int* in_sizes, int n_in,
                              void* d_out, int out_size, void* d_ws, size_t ws_size,
                              hipStream_t stream) {
  const int* x = (const int*)d_in[0];
  const int* y = (const int*)d_in[1];
  const float* We = (const float*)d_in[2];
  const float* Wp = (const float*)d_in[3];
  const float* bp = (const float*)d_in[4];
  const float* Wg = (const float*)d_in[5];
  const float* bg = (const float*)d_in[6];
  float* out = (float*)d_out;

  float* ws = (float*)d_ws;
  float* T = ws;              // 22*512 floats
  float* G = ws + 11264;      // 814 (22x37 padded)
  float* u = G + 814;         // 22
  float* v = u + 22;          // 22
  float* Ftots = v + 22;      // 16
  float* Fws = (float*)((char*)d_ws + (1 << 20));  // 16.78 MiB: F (diag-major)

  k_T<<<22, 512, 0, stream>>>(We, Wp, bp, T);
  k_G<<<22, 512, 0, stream>>>(T, Wg, G, u, v);

  const bool fused = ws_size >= ((size_t)35 << 20);
  if (fused) {
    float* Bws = (float*)((char*)d_ws + ((size_t)18 << 20));  // 16.78 MiB: suffix B
    k_nw<<<32, 512, 0, stream>>>(x, y, G, u, v, bg, Fws, Bws, Ftots);
    k_ET<<<16 * 64, 256, 0, stream>>>(Fws, Bws, Ftots, out);
  } else {
    float* Gws = out;  // suffix B parked in out (fallback path)
    k_nw<<<32, 512, 0, stream>>>(x, y, G, u, v, bg, Fws, Gws, Ftots);
    k_E<<<128, 512, 0, stream>>>(Gws, Ftots, Fws);
    k_tr<<<16 * 64, 256, 0, stream>>>(Fws, out);
  }
}